// Round 2
// baseline (3944.786 us; speedup 1.0000x reference)
//
#include <hip/hip_runtime.h>
#include <hip/hip_bf16.h>
#include <math.h>

using bf16 = __hip_bfloat16;
typedef __attribute__((ext_vector_type(4))) float f32x4;
typedef __attribute__((ext_vector_type(8))) short short8;

#define B_N 32
#define S_N 512
#define T_N 50
#define H_N 8
#define NL_N 4
#define VB_N 30000
#define ST_N 562
#define STP_N 576
#define NTOK_N (B_N*ST_N)   // 17984
#define CHK 4               // attention batch chunk

__device__ __forceinline__ float b2f(bf16 x){ return __bfloat162float(x); }
__device__ __forceinline__ bf16  f2b(float x){ return __float2bfloat16(x); }
// flag-aware raw-input load: f==1 -> buffer is float32, else bf16
__device__ __forceinline__ float ldw(const void* p, long i, int f){
    return f ? ((const float*)p)[i] : __bfloat162float(((const bf16*)p)[i]);
}

__device__ __forceinline__ void load_lds16(const void* g, void* l){
    __builtin_amdgcn_global_load_lds((const __attribute__((address_space(1))) void*)g,
                                     (__attribute__((address_space(3))) void*)l, 16, 0, 0);
}

// ---------------- dtype detector ----------------
__global__ __launch_bounds__(256) void detect_k(const unsigned int* __restrict__ w, int* flag)
{
    int t = threadIdx.x;
    float s = 0.f;
    for (int i=t;i<4096;i+=256){ int e = (w[i]>>7)&0xFF; s += fabsf((float)e - 120.f); }
    __shared__ float red[4];
    for (int o=32;o>0;o>>=1) s += __shfl_down(s,o,64);
    int wv=t>>6, lane=t&63;
    if (lane==0) red[wv]=s;
    __syncthreads();
    if (t==0) flag[0] = ((red[0]+red[1]+red[2]+red[3]) * (1.f/4096.f) > 20.f) ? 1 : 0;
}

// ---------------- topic memory ----------------
__global__ __launch_bounds__(256) void softmax_wdec_k(
    const void* __restrict__ Wd, const void* __restrict__ bd, float* __restrict__ wd,
    const int* __restrict__ flagp)
{
    const int isf = *flagp;
    int r = blockIdx.x, t = threadIdx.x;
    __shared__ float red[4];
    float mx = -1e30f;
    for (int c=t;c<VB_N;c+=256) mx = fmaxf(mx, ldw(Wd,(long)r*VB_N+c,isf) + ldw(bd,c,isf));
    for (int o=32;o>0;o>>=1) mx = fmaxf(mx, __shfl_down(mx,o,64));
    int w=t>>6, lane=t&63;
    if (lane==0) red[w]=mx;
    __syncthreads();
    mx = fmaxf(fmaxf(red[0],red[1]),fmaxf(red[2],red[3]));
    __syncthreads();
    float sm=0.f;
    for (int c=t;c<VB_N;c+=256) sm += __expf(ldw(Wd,(long)r*VB_N+c,isf) + ldw(bd,c,isf) - mx);
    for (int o=32;o>0;o>>=1) sm += __shfl_down(sm,o,64);
    if (lane==0) red[w]=sm;
    __syncthreads();
    float inv = 1.f/(red[0]+red[1]+red[2]+red[3]);
    for (int c=t;c<VB_N;c+=256)
        wd[(long)r*VB_N + c] = __expf(ldw(Wd,(long)r*VB_N+c,isf) + ldw(bd,c,isf) - mx)*inv;
}

__global__ void zero_f32_k(float* p, int n){
    int i = blockIdx.x*256 + threadIdx.x;
    if (i < n) p[i] = 0.f;
}

__global__ __launch_bounds__(256) void mem_fc1_k(
    const float* __restrict__ wd, const void* __restrict__ W1, float* __restrict__ hmem,
    const int* __restrict__ flagp)
{
    const int isf = *flagp;
    int c0 = blockIdx.x * 64;
    int t = threadIdx.x;
    int kq = t >> 6, c = t & 63;
    const int kchunk = (VB_N + 31)/32;     // 938
    int ks = blockIdx.y * kchunk;
    int ke = ks + kchunk; if (ke > VB_N) ke = VB_N;
    float acc[T_N];
    #pragma unroll
    for (int r=0;r<T_N;r++) acc[r]=0.f;
    for (int k = ks + kq; k < ke; k += 4) {
        float wv = ldw(W1,(long)k*1024 + c0 + c,isf);
        #pragma unroll
        for (int r=0;r<T_N;r++) acc[r] += wd[(long)r*VB_N + k] * wv;
    }
    __shared__ float red[4][64];
    for (int r=0;r<T_N;r++) {
        red[kq][c] = acc[r];
        __syncthreads();
        if (kq==0) atomicAdd(&hmem[r*1024 + c0 + c], red[0][c]+red[1][c]+red[2][c]+red[3][c]);
        __syncthreads();
    }
}

__global__ __launch_bounds__(256) void mem_fc2_ln_k(
    const float* __restrict__ hmem, const void* __restrict__ b1,
    const void* __restrict__ W2, const void* __restrict__ b2,
    const void* __restrict__ lg, const void* __restrict__ lb,
    float* __restrict__ tmf, bf16* __restrict__ tmb, const int* __restrict__ flagp)
{
    const int isf = *flagp;
    int r = blockIdx.x, t = threadIdx.x;
    float a0 = 0.f, a1 = 0.f;
    for (int k=0;k<1024;k++) {
        float h = fmaxf(hmem[r*1024+k] + ldw(b1,k,isf), 0.f);
        a0 += h * ldw(W2,k*512 + t,isf);
        a1 += h * ldw(W2,k*512 + t + 256,isf);
    }
    a0 += ldw(b2,t,isf); a1 += ldw(b2,t+256,isf);
    __shared__ float red[4];
    float s = a0 + a1;
    for (int o=32;o>0;o>>=1) s += __shfl_down(s,o,64);
    int w=t>>6, lane=t&63;
    if (lane==0) red[w]=s;
    __syncthreads();
    float mean = (red[0]+red[1]+red[2]+red[3]) * (1.f/512.f);
    float d0=a0-mean, d1=a1-mean;
    float q = d0*d0 + d1*d1;
    __syncthreads();
    for (int o=32;o>0;o>>=1) q += __shfl_down(q,o,64);
    if (lane==0) red[w]=q;
    __syncthreads();
    float var = (red[0]+red[1]+red[2]+red[3]) * (1.f/512.f);
    float rstd = rsqrtf(var + 1e-12f);
    float o0 = d0*rstd*ldw(lg,t,isf) + ldw(lb,t,isf);
    float o1 = d1*rstd*ldw(lg,t+256,isf) + ldw(lb,t+256,isf);
    tmf[r*512+t]=o0; tmf[r*512+t+256]=o1;
    tmb[r*512+t]=f2b(o0); tmb[r*512+t+256]=f2b(o1);
}

// ---------------- embedding + ragged insert ----------------
__global__ __launch_bounds__(256) void embed_insert_k(
    const int* __restrict__ ids, const int* __restrict__ lens,
    const void* __restrict__ embed, const float* __restrict__ tmf,
    const bf16* __restrict__ tmb, float* __restrict__ hf, bf16* __restrict__ hb,
    const int* __restrict__ flagp)
{
    const int isf = *flagp;
    int j = blockIdx.x, b = blockIdx.y, t = threadIdx.x;
    int L = lens[b]; L = L<1?1:(L>S_N?S_N:L);
    long orow = ((long)b*ST_N + j)*512;
    if (j >= L && j < L + T_N) {
        int m = j - L;
        for (int c=t;c<512;c+=256){ float v = tmf[m*512+c]; hf[orow+c]=v; hb[orow+c]=tmb[m*512+c]; }
    } else {
        int sj = (j < L) ? j : j - T_N;   // in [0, 511]
        int id = ids[b*S_N + sj];
        for (int c=t;c<512;c+=256){ float e = ldw(embed,(long)id*512+c,isf); hf[orow+c]=e; hb[orow+c]=f2b(e); }
    }
}

// ---------------- weight prep ----------------
__global__ __launch_bounds__(256) void transpose_k(
    const void* __restrict__ src, bf16* __restrict__ dst,
    int R, int C, long sstride, long dstride, const int* __restrict__ flagp)
{
    const int isf = *flagp;
    __shared__ bf16 tile[32][33];
    int n0 = blockIdx.x * 32, k0 = blockIdx.y * 32, z = blockIdx.z;
    int t = threadIdx.x;
    int nl = t & 31, kb = t >> 5;
    #pragma unroll
    for (int i=0;i<4;i++) {
        int k = kb + i*8;
        tile[k][nl] = f2b(ldw(src, z*sstride + (long)(k0+k)*C + n0+nl, isf));
    }
    __syncthreads();
    int kl = t & 31, nb = t >> 5;
    #pragma unroll
    for (int i=0;i<4;i++) {
        int n = nb + i*8;
        dst[z*dstride + (long)(n0+n)*R + k0+kl] = tile[kl][n];
    }
}

__global__ void concat_bias_k(const void* bq, const void* bk, const void* bv, bf16* out,
                              const int* __restrict__ flagp){
    const int isf = *flagp;
    int i = blockIdx.x*256 + threadIdx.x;
    if (i >= NL_N*1536) return;
    int l = i/1536, n = i%1536;
    float v = (n<512) ? ldw(bq,l*512+n,isf) : (n<1024 ? ldw(bk,l*512+n-512,isf) : ldw(bv,l*512+n-1024,isf));
    out[i] = f2b(v);
}

// Vt[z][n][k] chunk-local z; b = b0 + z/8, zero pad k>=562
__global__ __launch_bounds__(256) void transpose_v_k(
    const bf16* __restrict__ qkv, bf16* __restrict__ Vt, int b0)
{
    __shared__ bf16 tl[64*33];
    int k0 = blockIdx.x * 32, z = blockIdx.z;
    int b = b0 + (z >> 3), h = z & 7;
    int t = threadIdx.x;
    int n = t & 63, kb = t >> 6;
    #pragma unroll
    for (int i=0;i<8;i++) {
        int kl = kb + 4*i;
        int kg = k0 + kl;
        bf16 v = (kg < ST_N) ? qkv[((long)(b*ST_N + kg))*1536 + 1024 + h*64 + n] : f2b(0.f);
        tl[n*33 + kl] = v;
    }
    __syncthreads();
    int kk = t & 31, nb = t >> 5;
    #pragma unroll
    for (int i=0;i<8;i++) {
        int nn = nb + 8*i;
        Vt[((long)z*64 + nn)*STP_N + k0 + kk] = tl[nn*33 + kk];
    }
}

// ---------------- MFMA GEMM: C = A[M,K] @ Bt[N,K]^T ----------------
constexpr int EPI_BF16=0, EPI_F32=1, EPI_GELU=2, EPI_SCORES=3, EPI_CTX=4;

template<int BM, int BN, int MODE>
__global__ __launch_bounds__(256,2) void gemm_k(
    const bf16* __restrict__ Ag, const bf16* __restrict__ Bg, void* __restrict__ Cg,
    const void* __restrict__ bias, long bias_off, const int* __restrict__ seq_lens,
    int M, int N, int K, int lda, int ldb, int ldc, int Nst, int b0,
    const int* __restrict__ flagp)
{
    const int isf = *flagp;
    __shared__ bf16 lA[BM*32];
    __shared__ bf16 lB[BN*32];
    const int tid = threadIdx.x;
    const int tile_m = blockIdx.y * BM;
    const int tile_n = blockIdx.x * BN;

    const bf16* Ab = Ag;
    const bf16* Bb = Bg;
    bf16*  C16 = (bf16*)Cg;
    float* C32 = (float*)Cg;
    int lenT = 0;
    if constexpr (MODE == EPI_SCORES) {
        int z = blockIdx.z, b = b0 + (z>>3), h = z&7;
        Ab = Ag + (long)b*ST_N*1536 + h*64;             // q
        Bb = Bg + (long)b*ST_N*1536 + 512 + h*64;       // k
        C32 = (float*)Cg + (long)z*STP_N*STP_N;
        int L = seq_lens[b]; L = L<1?1:(L>S_N?S_N:L);
        lenT = L + T_N;
    } else if constexpr (MODE == EPI_CTX) {
        int z = blockIdx.z, b = b0 + (z>>3), h = z&7;
        Ab = Ag + (long)z*STP_N*STP_N*2;                // bf16 P packed in f32 S rows
        Bb = Bg + (long)z*64*STP_N;                     // Vt chunk-local
        C16 = (bf16*)Cg + (long)b*ST_N*512 + h*64;
    }

    constexpr int WM = BM/2, WN = BN/2, MI = WM/16, NI = WN/16;
    const int w = tid>>6, lane = tid&63;
    const int wm = w>>1, wn = w&1;
    const int quad = lane>>4, lrow = lane&15;

    f32x4 zero = {0.f,0.f,0.f,0.f};
    f32x4 acc[MI][NI];
    #pragma unroll
    for (int i=0;i<MI;i++)
        #pragma unroll
        for (int j=0;j<NI;j++) acc[i][j] = zero;

    for (int k0=0;k0<K;k0+=32) {
        __syncthreads();
        #pragma unroll
        for (int r=0;r<BM/64;r++) {
            int e = (r*256 + tid)*8;
            int row = e>>5, kk = e&31;
            int gr = tile_m + row; gr = gr < M ? gr : M-1;
            load_lds16(Ab + (long)gr*lda + k0 + kk, &lA[e]);
        }
        #pragma unroll
        for (int r=0;r<BN/64;r++) {
            int e = (r*256 + tid)*8;
            int row = e>>5, kk = e&31;
            int gr = tile_n + row; gr = gr < N ? gr : N-1;
            load_lds16(Bb + (long)gr*ldb + k0 + kk, &lB[e]);
        }
        __syncthreads();
        short8 afr[MI], bfr[NI];
        #pragma unroll
        for (int i=0;i<MI;i++) afr[i] = *(const short8*)&lA[(wm*WM + i*16 + lrow)*32 + quad*8];
        #pragma unroll
        for (int j=0;j<NI;j++) bfr[j] = *(const short8*)&lB[(wn*WN + j*16 + lrow)*32 + quad*8];
        #pragma unroll
        for (int i=0;i<MI;i++)
            #pragma unroll
            for (int j=0;j<NI;j++)
                acc[i][j] = __builtin_amdgcn_mfma_f32_16x16x32_bf16(afr[i], bfr[j], acc[i][j], 0, 0, 0);
    }

    #pragma unroll
    for (int i=0;i<MI;i++) {
        #pragma unroll
        for (int j=0;j<NI;j++) {
            int col = tile_n + wn*WN + j*16 + lrow;
            int rb  = tile_m + wm*WM + i*16 + quad*4;
            #pragma unroll
            for (int r=0;r<4;r++) {
                int row = rb + r;
                if (row >= M || col >= Nst) continue;
                float v = acc[i][j][r];
                if constexpr (MODE == EPI_BF16) {
                    C16[(long)row*ldc + col] = f2b(v + b2f(((const bf16*)bias)[bias_off + col]));
                } else if constexpr (MODE == EPI_F32) {
                    C32[(long)row*ldc + col] = v + ldw(bias, bias_off + col, isf);
                } else if constexpr (MODE == EPI_GELU) {
                    float x = v + ldw(bias, bias_off + col, isf);
                    C16[(long)row*ldc + col] = f2b(0.5f*x*(1.f + erff(x*0.70710678118654752f)));
                } else if constexpr (MODE == EPI_SCORES) {
                    C32[(long)row*ldc + col] = v*0.125f + (col < lenT ? 0.f : -10000.f);
                } else { // EPI_CTX
                    C16[(long)row*ldc + col] = f2b(v);
                }
            }
        }
    }
}

// ---------------- softmax over S rows (f32 in, bf16 P written in place) ----------------
__global__ __launch_bounds__(256) void softmax_s_k(float* __restrict__ S)
{
    int row = blockIdx.x, z = blockIdx.y, t = threadIdx.x;
    float* p = S + ((long)z*STP_N + row)*STP_N;
    bf16* p16 = (bf16*)p;
    float v0 = p[t];
    float v1 = p[t+256];
    float v2 = (t+512 < ST_N) ? p[t+512] : -1e30f;
    __shared__ float red[4];
    float mx = fmaxf(v0, fmaxf(v1, v2));
    for (int o=32;o>0;o>>=1) mx = fmaxf(mx, __shfl_down(mx,o,64));
    int w=t>>6, lane=t&63;
    if (lane==0) red[w]=mx;
    __syncthreads();
    mx = fmaxf(fmaxf(red[0],red[1]),fmaxf(red[2],red[3]));
    float e0 = __expf(v0-mx);
    float e1 = __expf(v1-mx);
    float e2 = (t+512 < ST_N) ? __expf(v2-mx) : 0.f;
    float s = e0+e1+e2;
    __syncthreads();
    for (int o=32;o>0;o>>=1) s += __shfl_down(s,o,64);
    if (lane==0) red[w]=s;
    __syncthreads();
    float inv = 1.f/(red[0]+red[1]+red[2]+red[3]);
    p16[t] = f2b(e0*inv);
    p16[t+256] = f2b(e1*inv);
    if (t+512 < STP_N) p16[t+512] = f2b(e2*inv);
}

// ---------------- residual + LN (fp32 state + bf16 shadow) ----------------
__global__ __launch_bounds__(256) void ln_residual_k(
    const float* __restrict__ tmp, float* __restrict__ hf, bf16* __restrict__ hb,
    const void* __restrict__ g, const void* __restrict__ bb, long goff,
    void* __restrict__ outp, int is_final, const int* __restrict__ flagp)
{
    const int isf = *flagp;
    const int of32 = is_final && isf;
    long base = (long)blockIdx.x * 512;
    int t = threadIdx.x;
    float v0 = hf[base+t]     + tmp[base+t];
    float v1 = hf[base+t+256] + tmp[base+t+256];
    __shared__ float red[4];
    float s = v0+v1;
    for (int o=32;o>0;o>>=1) s += __shfl_down(s,o,64);
    int w=t>>6, lane=t&63;
    if (lane==0) red[w]=s;
    __syncthreads();
    float mean = (red[0]+red[1]+red[2]+red[3]) * (1.f/512.f);
    float d0=v0-mean, d1=v1-mean;
    float q = d0*d0 + d1*d1;
    __syncthreads();
    for (int o=32;o>0;o>>=1) q += __shfl_down(q,o,64);
    if (lane==0) red[w]=q;
    __syncthreads();
    float var = (red[0]+red[1]+red[2]+red[3]) * (1.f/512.f);
    float rstd = rsqrtf(var + 1e-12f);
    float o0 = d0*rstd*ldw(g,goff+t,isf) + ldw(bb,goff+t,isf);
    float o1 = d1*rstd*ldw(g,goff+t+256,isf) + ldw(bb,goff+t+256,isf);
    hf[base+t]=o0; hf[base+t+256]=o1;
    hb[base+t]=f2b(o0); hb[base+t+256]=f2b(o1);
    if (of32) {
        ((float*)outp)[base+t]=o0; ((float*)outp)[base+t+256]=o1;
    } else {
        ((bf16*)outp)[base+t]=f2b(o0); ((bf16*)outp)[base+t+256]=f2b(o1);
    }
}

extern "C" void kernel_launch(void* const* d_in, const int* in_sizes, int n_in,
                              void* d_out, int out_size, void* d_ws, size_t ws_size,
                              hipStream_t stream)
{
    (void)in_sizes; (void)n_in; (void)out_size; (void)ws_size;
    const int*  ids   = (const int*) d_in[0];
    const int*  slens = (const int*) d_in[1];
    const void* embed = d_in[2];
    const void* Wdec  = d_in[3];
    const void* bdec  = d_in[4];
    const void* mW1   = d_in[5];
    const void* mb1   = d_in[6];
    const void* mW2   = d_in[7];
    const void* mb2   = d_in[8];
    const void* mlg   = d_in[9];
    const void* mlb   = d_in[10];
    const void* Wq    = d_in[11];
    const void* bq    = d_in[12];
    const void* Wk    = d_in[13];
    const void* bk    = d_in[14];
    const void* Wv    = d_in[15];
    const void* bv    = d_in[16];
    const void* Wo    = d_in[17];
    const void* bo    = d_in[18];
    const void* l1g   = d_in[19];
    const void* l1b   = d_in[20];
    const void* Wi    = d_in[21];
    const void* bi    = d_in[22];
    const void* Wf    = d_in[23];
    const void* bfv   = d_in[24];
    const void* l2g   = d_in[25];
    const void* l2b   = d_in[26];

    char* p = (char*)d_ws;
    auto alloc = [&](size_t bytes)->void* {
        void* r = (void*)p; p += (bytes + 255) & ~(size_t)255; return r; };
    int*   flag  = (int*)  alloc(256);
    float* tmf   = (float*)alloc((size_t)T_N*512*4);
    bf16*  tmb   = (bf16*) alloc((size_t)T_N*512*2);
    float* hmem  = (float*)alloc((size_t)T_N*1024*4);
    float* hidf  = (float*)alloc((size_t)NTOK_N*512*4);
    bf16*  hidb  = (bf16*) alloc((size_t)NTOK_N*512*2);
    bf16*  qkvt  = (bf16*) alloc((size_t)NL_N*1536*512*2);
    bf16*  wot   = (bf16*) alloc((size_t)NL_N*512*512*2);
    bf16*  wit   = (bf16*) alloc((size_t)NL_N*2048*512*2);
    bf16*  wft   = (bf16*) alloc((size_t)NL_N*512*2048*2);
    bf16*  bqkv  = (bf16*) alloc((size_t)NL_N*1536*2);
    bf16*  ctx   = (bf16*) alloc((size_t)NTOK_N*512*2);
    // R1 union: [qkv 55.25MB | Vt 2.36MB] <-> [ffb 73.7MB]
    char*  R1    = (char*) alloc((size_t)NTOK_N*2048*2);
    bf16*  qkv   = (bf16*)R1;
    bf16*  Vt    = (bf16*)(R1 + (size_t)NTOK_N*1536*2);
    bf16*  ffb   = (bf16*)R1;
    // R2 union: [wdist 6MB] <-> [Sb 42.5MB] <-> [tmpb 36.8MB]
    char*  R2    = (char*) alloc((size_t)CHK*8*STP_N*STP_N*4);
    float* wdist = (float*)R2;
    float* Sb    = (float*)R2;
    float* tmpb  = (float*)R2;
    // total ~= 216 MB

    detect_k<<<1,256,0,stream>>>((const unsigned int*)embed, flag);

    // topic memory
    softmax_wdec_k<<<T_N,256,0,stream>>>(Wdec,bdec,wdist,flag);
    zero_f32_k<<<(T_N*1024+255)/256,256,0,stream>>>(hmem, T_N*1024);
    mem_fc1_k<<<dim3(16,32),256,0,stream>>>(wdist, mW1, hmem, flag);
    mem_fc2_ln_k<<<T_N,256,0,stream>>>(hmem, mb1, mW2, mb2, mlg, mlb, tmf, tmb, flag);
    embed_insert_k<<<dim3(ST_N,B_N),256,0,stream>>>(ids, slens, embed, tmf, tmb, hidf, hidb, flag);

    // weight prep (canonical bf16, [N][K] layouts)
    transpose_k<<<dim3(16,16,NL_N),256,0,stream>>>(Wq, qkvt,          512, 512, 262144L, 786432L, flag);
    transpose_k<<<dim3(16,16,NL_N),256,0,stream>>>(Wk, qkvt+262144,   512, 512, 262144L, 786432L, flag);
    transpose_k<<<dim3(16,16,NL_N),256,0,stream>>>(Wv, qkvt+524288,   512, 512, 262144L, 786432L, flag);
    transpose_k<<<dim3(16,16,NL_N),256,0,stream>>>(Wo, wot,           512, 512, 262144L, 262144L, flag);
    transpose_k<<<dim3(64,16,NL_N),256,0,stream>>>(Wi, wit,           512, 2048, 1048576L, 1048576L, flag);
    transpose_k<<<dim3(16,64,NL_N),256,0,stream>>>(Wf, wft,           2048, 512, 1048576L, 1048576L, flag);
    concat_bias_k<<<(NL_N*1536+255)/256,256,0,stream>>>(bq,bk,bv,bqkv,flag);

    for (int l=0;l<NL_N;l++) {
        gemm_k<128,128,EPI_BF16><<<dim3(12,141,1),256,0,stream>>>(
            hidb, qkvt + (size_t)l*786432, qkv, bqkv, (long)l*1536, nullptr,
            NTOK_N, 1536, 512, 512, 512, 1536, 1536, 0, flag);
        for (int c0=0;c0<B_N;c0+=CHK) {
            transpose_v_k<<<dim3(18,1,CHK*8),256,0,stream>>>(qkv, Vt, c0);
            gemm_k<128,128,EPI_SCORES><<<dim3(5,5,CHK*8),256,0,stream>>>(
                qkv, qkv, Sb, nullptr, 0, slens,
                ST_N, ST_N, 64, 1536, 1536, STP_N, STP_N, c0, flag);
            softmax_s_k<<<dim3(ST_N,CHK*8),256,0,stream>>>(Sb);
            gemm_k<128,64,EPI_CTX><<<dim3(1,5,CHK*8),256,0,stream>>>(
                (const bf16*)Sb, Vt, ctx, nullptr, 0, nullptr,
                ST_N, 64, STP_N, 1152, STP_N, 512, 64, c0, flag);
        }
        gemm_k<128,128,EPI_F32><<<dim3(4,141,1),256,0,stream>>>(
            ctx, wot + (size_t)l*262144, tmpb, bo, (long)l*512, nullptr,
            NTOK_N, 512, 512, 512, 512, 512, 512, 0, flag);
        ln_residual_k<<<NTOK_N,256,0,stream>>>(tmpb, hidf, hidb, l1g, l1b, (long)l*512,
                                               hidb, 0, flag);
        gemm_k<128,128,EPI_GELU><<<dim3(16,141,1),256,0,stream>>>(
            hidb, wit + (size_t)l*1048576, ffb, bi, (long)l*2048, nullptr,
            NTOK_N, 2048, 512, 512, 512, 2048, 2048, 0, flag);
        gemm_k<128,128,EPI_F32><<<dim3(4,141,1),256,0,stream>>>(
            ffb, wft + (size_t)l*1048576, tmpb, bfv, (long)l*512, nullptr,
            NTOK_N, 512, 2048, 2048, 2048, 512, 512, 0, flag);
        ln_residual_k<<<NTOK_N,256,0,stream>>>(tmpb, hidf, hidb, l2g, l2b, (long)l*512,
                                               (l == NL_N-1) ? d_out : (void*)hidb,
                                               (l == NL_N-1) ? 1 : 0, flag);
    }
}

// Round 3
// 2349.652 us; speedup vs baseline: 1.6789x; 1.6789x over previous
//
#include <hip/hip_runtime.h>
#include <hip/hip_bf16.h>
#include <math.h>

using bf16 = __hip_bfloat16;
typedef __attribute__((ext_vector_type(4))) float f32x4;
typedef __attribute__((ext_vector_type(8))) short short8;

#define B_N 32
#define S_N 512
#define T_N 50
#define H_N 8
#define NL_N 4
#define VB_N 30000
#define VBP_N 30016          // VB padded to mult of 32
#define ST_N 562
#define STP_N 576
#define NTOK_N (B_N*ST_N)   // 17984

__device__ __forceinline__ float b2f(bf16 x){ return __bfloat162float(x); }
__device__ __forceinline__ bf16  f2b(float x){ return __float2bfloat16(x); }
// flag-aware raw-input load: f==1 -> buffer is float32, else bf16
__device__ __forceinline__ float ldw(const void* p, long i, int f){
    return f ? ((const float*)p)[i] : __bfloat162float(((const bf16*)p)[i]);
}

__device__ __forceinline__ void load_lds16(const void* g, void* l){
    __builtin_amdgcn_global_load_lds((const __attribute__((address_space(1))) void*)g,
                                     (__attribute__((address_space(3))) void*)l, 16, 0, 0);
}

// ---------------- dtype detector ----------------
__global__ __launch_bounds__(256) void detect_k(const unsigned int* __restrict__ w, int* flag)
{
    int t = threadIdx.x;
    float s = 0.f;
    for (int i=t;i<4096;i+=256){ int e = (w[i]>>7)&0xFF; s += fabsf((float)e - 120.f); }
    __shared__ float red[4];
    for (int o=32;o>0;o>>=1) s += __shfl_down(s,o,64);
    int wv=t>>6, lane=t&63;
    if (lane==0) red[wv]=s;
    __syncthreads();
    if (t==0) flag[0] = ((red[0]+red[1]+red[2]+red[3]) * (1.f/4096.f) > 20.f) ? 1 : 0;
}

__global__ void zero_u32_k(unsigned int* p, long n){
    long i = (long)blockIdx.x*256 + threadIdx.x;
    if (i < n) p[i] = 0u;
}

// ---------------- topic memory ----------------
// writes softmax rows as bf16 into wdb [64][VBP_N] (rows 50..63 and cols >=VB_N pre-zeroed)
__global__ __launch_bounds__(256) void softmax_wdec_k(
    const void* __restrict__ Wd, const void* __restrict__ bd, bf16* __restrict__ wdb,
    const int* __restrict__ flagp)
{
    const int isf = *flagp;
    int r = blockIdx.x, t = threadIdx.x;
    __shared__ float red[4];
    float mx = -1e30f;
    for (int c=t;c<VB_N;c+=256) mx = fmaxf(mx, ldw(Wd,(long)r*VB_N+c,isf) + ldw(bd,c,isf));
    for (int o=32;o>0;o>>=1) mx = fmaxf(mx, __shfl_down(mx,o,64));
    int w=t>>6, lane=t&63;
    if (lane==0) red[w]=mx;
    __syncthreads();
    mx = fmaxf(fmaxf(red[0],red[1]),fmaxf(red[2],red[3]));
    __syncthreads();
    float sm=0.f;
    for (int c=t;c<VB_N;c+=256) sm += __expf(ldw(Wd,(long)r*VB_N+c,isf) + ldw(bd,c,isf) - mx);
    for (int o=32;o>0;o>>=1) sm += __shfl_down(sm,o,64);
    if (lane==0) red[w]=sm;
    __syncthreads();
    float inv = 1.f/(red[0]+red[1]+red[2]+red[3]);
    for (int c=t;c<VB_N;c+=256)
        wdb[(long)r*VBP_N + c] = f2b(__expf(ldw(Wd,(long)r*VB_N+c,isf) + ldw(bd,c,isf) - mx)*inv);
}

__global__ __launch_bounds__(256) void mem_fc2_ln_k(
    const float* __restrict__ hmem, const void* __restrict__ b1,
    const void* __restrict__ W2, const void* __restrict__ b2,
    const void* __restrict__ lg, const void* __restrict__ lb,
    float* __restrict__ tmf, bf16* __restrict__ tmb, const int* __restrict__ flagp)
{
    const int isf = *flagp;
    int r = blockIdx.x, t = threadIdx.x;
    float a0 = 0.f, a1 = 0.f;
    for (int k=0;k<1024;k++) {
        float h = fmaxf(hmem[r*1024+k] + ldw(b1,k,isf), 0.f);
        a0 += h * ldw(W2,k*512 + t,isf);
        a1 += h * ldw(W2,k*512 + t + 256,isf);
    }
    a0 += ldw(b2,t,isf); a1 += ldw(b2,t+256,isf);
    __shared__ float red[4];
    float s = a0 + a1;
    for (int o=32;o>0;o>>=1) s += __shfl_down(s,o,64);
    int w=t>>6, lane=t&63;
    if (lane==0) red[w]=s;
    __syncthreads();
    float mean = (red[0]+red[1]+red[2]+red[3]) * (1.f/512.f);
    float d0=a0-mean, d1=a1-mean;
    float q = d0*d0 + d1*d1;
    __syncthreads();
    for (int o=32;o>0;o>>=1) q += __shfl_down(q,o,64);
    if (lane==0) red[w]=q;
    __syncthreads();
    float var = (red[0]+red[1]+red[2]+red[3]) * (1.f/512.f);
    float rstd = rsqrtf(var + 1e-12f);
    float o0 = d0*rstd*ldw(lg,t,isf) + ldw(lb,t,isf);
    float o1 = d1*rstd*ldw(lg,t+256,isf) + ldw(lb,t+256,isf);
    tmf[r*512+t]=o0; tmf[r*512+t+256]=o1;
    tmb[r*512+t]=f2b(o0); tmb[r*512+t+256]=f2b(o1);
}

// ---------------- embedding + ragged insert ----------------
__global__ __launch_bounds__(256) void embed_insert_k(
    const int* __restrict__ ids, const int* __restrict__ lens,
    const void* __restrict__ embed, const float* __restrict__ tmf,
    const bf16* __restrict__ tmb, float* __restrict__ hf, bf16* __restrict__ hb,
    const int* __restrict__ flagp)
{
    const int isf = *flagp;
    int j = blockIdx.x, b = blockIdx.y, t = threadIdx.x;
    int L = lens[b]; L = L<1?1:(L>S_N?S_N:L);
    long orow = ((long)b*ST_N + j)*512;
    if (j >= L && j < L + T_N) {
        int m = j - L;
        for (int c=t;c<512;c+=256){ float v = tmf[m*512+c]; hf[orow+c]=v; hb[orow+c]=tmb[m*512+c]; }
    } else {
        int sj = (j < L) ? j : j - T_N;   // in [0, 511]
        int id = ids[b*S_N + sj];
        for (int c=t;c<512;c+=256){ float e = ldw(embed,(long)id*512+c,isf); hf[orow+c]=e; hb[orow+c]=f2b(e); }
    }
}

// ---------------- weight prep ----------------
// dst[z*dstride + (n0+n)*R + (k0+k)] = src[z*sstride + min(k0+k,Ksrc-1)*C + (n0+n)]
__global__ __launch_bounds__(256) void transpose_k(
    const void* __restrict__ src, bf16* __restrict__ dst,
    int R, int C, long sstride, long dstride, int Ksrc, const int* __restrict__ flagp)
{
    const int isf = *flagp;
    __shared__ bf16 tile[32][33];
    int n0 = blockIdx.x * 32, k0 = blockIdx.y * 32, z = blockIdx.z;
    int t = threadIdx.x;
    int nl = t & 31, kb = t >> 5;
    #pragma unroll
    for (int i=0;i<4;i++) {
        int k = k0 + kb + i*8; k = k < Ksrc ? k : Ksrc-1;
        tile[kb+i*8][nl] = f2b(ldw(src, z*sstride + (long)k*C + n0+nl, isf));
    }
    __syncthreads();
    int kl = t & 31, nb = t >> 5;
    #pragma unroll
    for (int i=0;i<4;i++) {
        int n = nb + i*8;
        dst[z*dstride + (long)(n0+n)*R + k0+kl] = tile[kl][n];
    }
}

__global__ void concat_bias_k(const void* bq, const void* bk, const void* bv, bf16* out,
                              const int* __restrict__ flagp){
    const int isf = *flagp;
    int i = blockIdx.x*256 + threadIdx.x;
    if (i >= NL_N*1536) return;
    int l = i/1536, n = i%1536;
    float v = (n<512) ? ldw(bq,l*512+n,isf) : (n<1024 ? ldw(bk,l*512+n-512,isf) : ldw(bv,l*512+n-1024,isf));
    out[i] = f2b(v);
}

// Vt[z][n][k]: n = head dim (64), k = key (576, zero pad k>=562); z = b*8+h over all 256
__global__ __launch_bounds__(256) void transpose_v_k(
    const bf16* __restrict__ qkv, bf16* __restrict__ Vt)
{
    __shared__ bf16 tl[64*33];
    int k0 = blockIdx.x * 32, z = blockIdx.z;
    int b = z >> 3, h = z & 7;
    int t = threadIdx.x;
    int n = t & 63, kb = t >> 6;
    #pragma unroll
    for (int i=0;i<8;i++) {
        int kl = kb + 4*i;
        int kg = k0 + kl;
        bf16 v = (kg < ST_N) ? qkv[((long)(b*ST_N + kg))*1536 + 1024 + h*64 + n] : f2b(0.f);
        tl[n*33 + kl] = v;
    }
    __syncthreads();
    int kk = t & 31, nb = t >> 5;
    #pragma unroll
    for (int i=0;i<8;i++) {
        int nn = nb + 8*i;
        Vt[((long)z*64 + nn)*STP_N + k0 + kk] = tl[nn*33 + kk];
    }
}

// ---------------- MFMA GEMM: C = A[M,K] @ Bt[N,K]^T ----------------
constexpr int EPI_BF16=0, EPI_F32=1, EPI_GELU=2, EPI_ATOMIC=3;

template<int BM, int BN, int MODE>
__global__ __launch_bounds__(256,2) void gemm_k(
    const bf16* __restrict__ Ag, const bf16* __restrict__ Bg, void* __restrict__ Cg,
    const void* __restrict__ bias, long bias_off,
    int M, int N, int K, int lda, int ldb, int ldc, int Nst, int kch,
    const int* __restrict__ flagp)
{
    const int isf = *flagp;
    __shared__ bf16 lA[BM*32];
    __shared__ bf16 lB[BN*32];
    const int tid = threadIdx.x;
    const int tile_m = blockIdx.y * BM;
    const int tile_n = blockIdx.x * BN;

    bf16*  C16 = (bf16*)Cg;
    float* C32 = (float*)Cg;

    constexpr int WM = BM/2, WN = BN/2, MI = WM/16, NI = WN/16;
    const int w = tid>>6, lane = tid&63;
    const int wm = w>>1, wn = w&1;
    const int quad = lane>>4, lrow = lane&15;

    f32x4 zero = {0.f,0.f,0.f,0.f};
    f32x4 acc[MI][NI];
    #pragma unroll
    for (int i=0;i<MI;i++)
        #pragma unroll
        for (int j=0;j<NI;j++) acc[i][j] = zero;

    int ks = 0, ke = K;
    if (kch > 0) { ks = blockIdx.z * kch; ke = ks + kch; if (ke > K) ke = K; }

    for (int k0=ks;k0<ke;k0+=32) {
        __syncthreads();
        #pragma unroll
        for (int r=0;r<BM/64;r++) {
            int e = (r*256 + tid)*8;
            int row = e>>5, kk = e&31;
            int gr = tile_m + row; gr = gr < M ? gr : M-1;
            load_lds16(Ag + (long)gr*lda + k0 + kk, &lA[e]);
        }
        #pragma unroll
        for (int r=0;r<BN/64;r++) {
            int e = (r*256 + tid)*8;
            int row = e>>5, kk = e&31;
            int gr = tile_n + row; gr = gr < N ? gr : N-1;
            load_lds16(Bg + (long)gr*ldb + k0 + kk, &lB[e]);
        }
        __syncthreads();
        short8 afr[MI], bfr[NI];
        #pragma unroll
        for (int i=0;i<MI;i++) afr[i] = *(const short8*)&lA[(wm*WM + i*16 + lrow)*32 + quad*8];
        #pragma unroll
        for (int j=0;j<NI;j++) bfr[j] = *(const short8*)&lB[(wn*WN + j*16 + lrow)*32 + quad*8];
        #pragma unroll
        for (int i=0;i<MI;i++)
            #pragma unroll
            for (int j=0;j<NI;j++)
                acc[i][j] = __builtin_amdgcn_mfma_f32_16x16x32_bf16(afr[i], bfr[j], acc[i][j], 0, 0, 0);
    }

    #pragma unroll
    for (int i=0;i<MI;i++) {
        #pragma unroll
        for (int j=0;j<NI;j++) {
            int col = tile_n + wn*WN + j*16 + lrow;
            int rb  = tile_m + wm*WM + i*16 + quad*4;
            #pragma unroll
            for (int r=0;r<4;r++) {
                int row = rb + r;
                if (row >= M || col >= Nst) continue;
                float v = acc[i][j][r];
                if constexpr (MODE == EPI_BF16) {
                    C16[(long)row*ldc + col] = f2b(v + b2f(((const bf16*)bias)[bias_off + col]));
                } else if constexpr (MODE == EPI_F32) {
                    C32[(long)row*ldc + col] = v + ldw(bias, bias_off + col, isf);
                } else if constexpr (MODE == EPI_GELU) {
                    float x = v + ldw(bias, bias_off + col, isf);
                    C16[(long)row*ldc + col] = f2b(0.5f*x*(1.f + erff(x*0.70710678118654752f)));
                } else { // EPI_ATOMIC
                    atomicAdd(&C32[(long)row*ldc + col], v);
                }
            }
        }
    }
}

// ---------------- flash attention ----------------
// grid: x = q-tile (0..4), z = b*8+h (0..255). 256 threads = 4 waves, wave owns 32 q rows.
// LDS rows are 64 bf16 with XOR-swizzled 8-elem chunks: chunk' = chunk ^ (row&7).
__global__ __launch_bounds__(256,2) void flash_k(
    const bf16* __restrict__ qkv, const bf16* __restrict__ Vt,
    bf16* __restrict__ ctx, const int* __restrict__ slens)
{
    __shared__ __align__(16) bf16 lQ[128*64];
    __shared__ __align__(16) bf16 lK[64*64];
    __shared__ __align__(16) bf16 lV[64*64];
    __shared__ __align__(16) bf16 lP[128*64];
    const int z = blockIdx.z, b = z>>3, h = z&7;
    const int qt = blockIdx.x;
    const int tid = threadIdx.x;
    const int w = tid>>6, lane = tid&63;
    const int quad = lane>>4, l15 = lane&15;
    int L = slens[b]; L = L<1?1:(L>S_N?S_N:L);
    const int lenT = L + T_N;

    // stage Q once (swizzled source chunk keeps LDS dest contiguous)
    #pragma unroll
    for (int rr=0;rr<4;rr++){
        int ci = rr*256 + tid;
        int row = ci>>3, c8 = (ci&7) ^ (row&7);
        int gr = qt*128 + row; gr = gr < ST_N ? gr : ST_N-1;
        load_lds16(qkv + ((long)(b*ST_N+gr))*1536 + h*64 + c8*8, &lQ[ci*8]);
    }

    f32x4 zerov = {0.f,0.f,0.f,0.f};
    f32x4 O[2][4];
    float m_i[2][4], l_i[2][4];
    #pragma unroll
    for (int i=0;i<2;i++){
        #pragma unroll
        for (int j=0;j<4;j++) O[i][j] = zerov;
        #pragma unroll
        for (int r=0;r<4;r++){ m_i[i][r]=-1e30f; l_i[i][r]=0.f; }
    }

    for (int kt=0; kt<9; kt++){
        __syncthreads();   // protect lK/lV/lP from prior-iter readers
        #pragma unroll
        for (int rr=0;rr<2;rr++){
            int ci = rr*256+tid;
            int row = ci>>3, c8 = (ci&7) ^ (row&7);
            int kr = kt*64+row; kr = kr < ST_N ? kr : ST_N-1;
            load_lds16(qkv + ((long)(b*ST_N+kr))*1536 + 512 + h*64 + c8*8, &lK[ci*8]);
        }
        #pragma unroll
        for (int rr=0;rr<2;rr++){
            int ci = rr*256+tid;
            int n = ci>>3, c8 = (ci&7) ^ (n&7);
            load_lds16(Vt + ((long)z*64+n)*STP_N + kt*64 + c8*8, &lV[ci*8]);
        }
        __syncthreads();

        // S = Q @ K^T  (S rows: quad*4+reg; cols: l15)
        f32x4 S[2][4];
        #pragma unroll
        for (int i=0;i<2;i++)
            #pragma unroll
            for (int j=0;j<4;j++) S[i][j] = zerov;
        #pragma unroll
        for (int kc=0;kc<2;kc++){
            short8 aQ[2], bK[4];
            #pragma unroll
            for (int i=0;i<2;i++){
                int row = w*32+i*16+l15;
                aQ[i] = *(const short8*)&lQ[row*64 + (((kc*4+quad) ^ (row&7))<<3)];
            }
            #pragma unroll
            for (int j=0;j<4;j++){
                int row = j*16+l15;
                bK[j] = *(const short8*)&lK[row*64 + (((kc*4+quad) ^ (row&7))<<3)];
            }
            #pragma unroll
            for (int i=0;i<2;i++)
                #pragma unroll
                for (int j=0;j<4;j++)
                    S[i][j] = __builtin_amdgcn_mfma_f32_16x16x32_bf16(aQ[i], bK[j], S[i][j], 0,0,0);
        }

        // scale + mask + online softmax stats (row lives across lanes 0..15 within quad group)
        #pragma unroll
        for (int i=0;i<2;i++){
            #pragma unroll
            for (int r=0;r<4;r++){
                float mx = -1e30f;
                #pragma unroll
                for (int j=0;j<4;j++){
                    int col = kt*64 + j*16 + l15;
                    float s = S[i][j][r]*0.125f + (col < lenT ? 0.f : -10000.f);
                    S[i][j][r] = s;
                    mx = fmaxf(mx, s);
                }
                #pragma unroll
                for (int o=1;o<16;o<<=1) mx = fmaxf(mx, __shfl_xor(mx, o, 64));
                float mn = fmaxf(m_i[i][r], mx);
                float alpha = __expf(m_i[i][r] - mn);
                m_i[i][r] = mn;
                float sm = 0.f;
                #pragma unroll
                for (int j=0;j<4;j++){
                    float pv = __expf(S[i][j][r] - mn);
                    S[i][j][r] = pv;
                    sm += pv;
                }
                #pragma unroll
                for (int o=1;o<16;o<<=1) sm += __shfl_xor(sm, o, 64);
                l_i[i][r] = l_i[i][r]*alpha + sm;
                #pragma unroll
                for (int j=0;j<4;j++) O[i][j][r] *= alpha;
            }
        }

        // P (C-layout) -> LDS (A-layout read next), swizzled
        #pragma unroll
        for (int i=0;i<2;i++)
            #pragma unroll
            for (int j=0;j<4;j++)
                #pragma unroll
                for (int r=0;r<4;r++){
                    int row = w*32 + i*16 + quad*4 + r;
                    int col = j*16 + l15;
                    lP[row*64 + (((col>>3) ^ (row&7))<<3) + (col&7)] = f2b(S[i][j][r]);
                }
        __syncthreads();

        // O += P @ V   (contraction over keys; B = Vt rows = head dims)
        #pragma unroll
        for (int kc=0;kc<2;kc++){
            short8 aP[2], bV[4];
            #pragma unroll
            for (int i=0;i<2;i++){
                int row = w*32+i*16+l15;
                aP[i] = *(const short8*)&lP[row*64 + (((kc*4+quad) ^ (row&7))<<3)];
            }
            #pragma unroll
            for (int j=0;j<4;j++){
                int row = j*16+l15;
                bV[j] = *(const short8*)&lV[row*64 + (((kc*4+quad) ^ (row&7))<<3)];
            }
            #pragma unroll
            for (int i=0;i<2;i++)
                #pragma unroll
                for (int j=0;j<4;j++)
                    O[i][j] = __builtin_amdgcn_mfma_f32_16x16x32_bf16(aP[i], bV[j], O[i][j], 0,0,0);
        }
    }

    #pragma unroll
    for (int i=0;i<2;i++)
        #pragma unroll
        for (int j=0;j<4;j++)
            #pragma unroll
            for (int r=0;r<4;r++){
                int row = qt*128 + w*32 + i*16 + quad*4 + r;
                if (row < ST_N)
                    ctx[((long)(b*ST_N+row))*512 + h*64 + j*16 + l15] = f2b(O[i][j][r] / l_i[i][r]);
            }
}

// ---------------- residual + LN (fp32 state + bf16 shadow) ----------------
__global__ __launch_bounds__(256) void ln_residual_k(
    const float* __restrict__ tmp, float* __restrict__ hf, bf16* __restrict__ hb,
    const void* __restrict__ g, const void* __restrict__ bb, long goff,
    void* __restrict__ outp, int is_final, const int* __restrict__ flagp)
{
    const int isf = *flagp;
    const int of32 = is_final && isf;
    long base = (long)blockIdx.x * 512;
    int t = threadIdx.x;
    float v0 = hf[base+t]     + tmp[base+t];
    float v1 = hf[base+t+256] + tmp[base+t+256];
    __shared__ float red[4];
    float s = v0+v1;
    for (int o=32;o>0;o>>=1) s += __shfl_down(s,o,64);
    int w=t>>6, lane=t&63;
    if (lane==0) red[w]=s;
    __syncthreads();
    float mean = (red[0]+red[1]+red[2]+red[3]) * (1.f/512.f);
    float d0=v0-mean, d1=v1-mean;
    float q = d0*d0 + d1*d1;
    __syncthreads();
    for (int o=32;o>0;o>>=1) q += __shfl_down(q,o,64);
    if (lane==0) red[w]=q;
    __syncthreads();
    float var = (red[0]+red[1]+red[2]+red[3]) * (1.f/512.f);
    float rstd = rsqrtf(var + 1e-12f);
    float o0 = d0*rstd*ldw(g,goff+t,isf) + ldw(bb,goff+t,isf);
    float o1 = d1*rstd*ldw(g,goff+t+256,isf) + ldw(bb,goff+t+256,isf);
    hf[base+t]=o0; hf[base+t+256]=o1;
    hb[base+t]=f2b(o0); hb[base+t+256]=f2b(o1);
    if (of32) {
        ((float*)outp)[base+t]=o0; ((float*)outp)[base+t+256]=o1;
    } else {
        ((bf16*)outp)[base+t]=f2b(o0); ((bf16*)outp)[base+t+256]=f2b(o1);
    }
}

extern "C" void kernel_launch(void* const* d_in, const int* in_sizes, int n_in,
                              void* d_out, int out_size, void* d_ws, size_t ws_size,
                              hipStream_t stream)
{
    (void)in_sizes; (void)n_in; (void)out_size; (void)ws_size;
    const int*  ids   = (const int*) d_in[0];
    const int*  slens = (const int*) d_in[1];
    const void* embed = d_in[2];
    const void* Wdec  = d_in[3];
    const void* bdec  = d_in[4];
    const void* mW1   = d_in[5];
    const void* mb1   = d_in[6];
    const void* mW2   = d_in[7];
    const void* mb2   = d_in[8];
    const void* mlg   = d_in[9];
    const void* mlb   = d_in[10];
    const void* Wq    = d_in[11];
    const void* bq    = d_in[12];
    const void* Wk    = d_in[13];
    const void* bk    = d_in[14];
    const void* Wv    = d_in[15];
    const void* bv    = d_in[16];
    const void* Wo    = d_in[17];
    const void* bo    = d_in[18];
    const void* l1g   = d_in[19];
    const void* l1b   = d_in[20];
    const void* Wi    = d_in[21];
    const void* bi    = d_in[22];
    const void* Wf    = d_in[23];
    const void* bfv   = d_in[24];
    const void* l2g   = d_in[25];
    const void* l2b   = d_in[26];

    char* p = (char*)d_ws;
    auto alloc = [&](size_t bytes)->void* {
        void* r = (void*)p; p += (bytes + 255) & ~(size_t)255; return r; };
    int*   flag  = (int*)  alloc(256);
    float* tmf   = (float*)alloc((size_t)T_N*512*4);
    bf16*  tmb   = (bf16*) alloc((size_t)T_N*512*2);
    float* hmem  = (float*)alloc((size_t)64*1024*4);
    float* hidf  = (float*)alloc((size_t)NTOK_N*512*4);
    bf16*  hidb  = (bf16*) alloc((size_t)NTOK_N*512*2);
    bf16*  qkvt  = (bf16*) alloc((size_t)NL_N*1536*512*2);
    bf16*  wot   = (bf16*) alloc((size_t)NL_N*512*512*2);
    bf16*  wit   = (bf16*) alloc((size_t)NL_N*2048*512*2);
    bf16*  wft   = (bf16*) alloc((size_t)NL_N*512*2048*2);
    bf16*  bqkv  = (bf16*) alloc((size_t)NL_N*1536*2);
    // R1 union (time-disjoint): prelude [wdb 3.84M | W1t 61.5M] <-> [qkv 55.25M] <-> [ffb 73.66M]
    char*  R1    = (char*) alloc((size_t)NTOK_N*2048*2);
    bf16*  wdb   = (bf16*)R1;
    bf16*  W1t   = (bf16*)(R1 + (size_t)64*VBP_N*2);
    bf16*  qkv   = (bf16*)R1;
    bf16*  ffb   = (bf16*)R1;
    // RU2: ctx (18.42M) + [Vt 18.87M <-> tmpb 36.83M]
    bf16*  ctx   = (bf16*) alloc((size_t)NTOK_N*512*2);
    char*  RU2   = (char*) alloc((size_t)NTOK_N*512*4);
    bf16*  Vt    = (bf16*)RU2;
    float* tmpb  = (float*)RU2;
    // total ~= 210 MB

    detect_k<<<1,256,0,stream>>>((const unsigned int*)embed, flag);

    // topic memory: softmax -> FC1 (MFMA, K-split atomic) -> FC2+LN
    zero_u32_k<<<((64L*VBP_N/2)+255)/256,256,0,stream>>>((unsigned int*)wdb, 64L*VBP_N/2);
    zero_u32_k<<<((64L*1024)+255)/256,256,0,stream>>>((unsigned int*)hmem, 64L*1024);
    softmax_wdec_k<<<T_N,256,0,stream>>>(Wdec,bdec,wdb,flag);
    // W1t[n][k] = W1[k][n], n<1024, k<30016 (clamped)
    transpose_k<<<dim3(32,VBP_N/32,1),256,0,stream>>>(mW1, W1t, VBP_N, 1024, 0L, 0L, VB_N, flag);
    gemm_k<64,128,EPI_ATOMIC><<<dim3(8,1,32),256,0,stream>>>(
        wdb, W1t, hmem, nullptr, 0,
        64, 1024, VBP_N, VBP_N, VBP_N, 1024, 1024, 960, flag);
    mem_fc2_ln_k<<<T_N,256,0,stream>>>(hmem, mb1, mW2, mb2, mlg, mlb, tmf, tmb, flag);
    embed_insert_k<<<dim3(ST_N,B_N),256,0,stream>>>(ids, slens, embed, tmf, tmb, hidf, hidb, flag);

    // weight prep (canonical bf16, [N][K] layouts)
    transpose_k<<<dim3(16,16,NL_N),256,0,stream>>>(Wq, qkvt,          512, 512, 262144L, 786432L, 512, flag);
    transpose_k<<<dim3(16,16,NL_N),256,0,stream>>>(Wk, qkvt+262144,   512, 512, 262144L, 786432L, 512, flag);
    transpose_k<<<dim3(16,16,NL_N),256,0,stream>>>(Wv, qkvt+524288,   512, 512, 262144L, 786432L, 512, flag);
    transpose_k<<<dim3(16,16,NL_N),256,0,stream>>>(Wo, wot,           512, 512, 262144L, 262144L, 512, flag);
    transpose_k<<<dim3(64,16,NL_N),256,0,stream>>>(Wi, wit,           512, 2048, 1048576L, 1048576L, 512, flag);
    transpose_k<<<dim3(16,64,NL_N),256,0,stream>>>(Wf, wft,           2048, 512, 1048576L, 1048576L, 2048, flag);
    concat_bias_k<<<(NL_N*1536+255)/256,256,0,stream>>>(bq,bk,bv,bqkv,flag);

    for (int l=0;l<NL_N;l++) {
        gemm_k<128,128,EPI_BF16><<<dim3(12,141,1),256,0,stream>>>(
            hidb, qkvt + (size_t)l*786432, qkv, bqkv, (long)l*1536,
            NTOK_N, 1536, 512, 512, 512, 1536, 1536, 0, flag);
        transpose_v_k<<<dim3(18,1,256),256,0,stream>>>(qkv, Vt);
        flash_k<<<dim3(5,1,256),256,0,stream>>>(qkv, Vt, ctx, slens);
        gemm_k<128,128,EPI_F32><<<dim3(4,141,1),256,0,stream>>>(
            ctx, wot + (size_t)l*262144, tmpb, bo, (long)l*512,
            NTOK_N, 512, 512, 512, 512, 512, 512, 0, flag);
        ln_residual_k<<<NTOK_N,256,0,stream>>>(tmpb, hidf, hidb, l1g, l1b, (long)l*512,
                                               hidb, 0, flag);
        gemm_k<128,128,EPI_GELU><<<dim3(16,141,1),256,0,stream>>>(
            hidb, wit + (size_t)l*1048576, ffb, bi, (long)l*2048,
            NTOK_N, 2048, 512, 512, 512, 2048, 2048, 0, flag);
        gemm_k<128,128,EPI_F32><<<dim3(4,141,1),256,0,stream>>>(
            ffb, wft + (size_t)l*1048576, tmpb, bfv, (long)l*512,
            NTOK_N, 512, 2048, 2048, 2048, 512, 512, 0, flag);
        ln_residual_k<<<NTOK_N,256,0,stream>>>(tmpb, hidf, hidb, l2g, l2b, (long)l*512,
                                               (l == NL_N-1) ? d_out : (void*)hidb,
                                               (l == NL_N-1) ? 1 : 0, flag);
    }
}

// Round 4
// 2068.070 us; speedup vs baseline: 1.9075x; 1.1362x over previous
//
#include <hip/hip_runtime.h>
#include <hip/hip_bf16.h>
#include <math.h>

using bf16 = __hip_bfloat16;
typedef __attribute__((ext_vector_type(4))) float f32x4;
typedef __attribute__((ext_vector_type(8))) short short8;

#define B_N 32
#define S_N 512
#define T_N 50
#define H_N 8
#define NL_N 4
#define VB_N 30000
#define VBP_N 30016          // VB padded to mult of 32
#define ST_N 562
#define STP_N 576
#define NTOK_N (B_N*ST_N)   // 17984

__device__ __forceinline__ float b2f(bf16 x){ return __bfloat162float(x); }
__device__ __forceinline__ bf16  f2b(float x){ return __float2bfloat16(x); }
// flag-aware raw-input load: f==1 -> buffer is float32, else bf16
__device__ __forceinline__ float ldw(const void* p, long i, int f){
    return f ? ((const float*)p)[i] : __bfloat162float(((const bf16*)p)[i]);
}

__device__ __forceinline__ void load_lds16(const void* g, void* l){
    __builtin_amdgcn_global_load_lds((const __attribute__((address_space(1))) void*)g,
                                     (__attribute__((address_space(3))) void*)l, 16, 0, 0);
}

// ---------------- dtype detector ----------------
__global__ __launch_bounds__(256) void detect_k(const unsigned int* __restrict__ w, int* flag)
{
    int t = threadIdx.x;
    float s = 0.f;
    for (int i=t;i<4096;i+=256){ int e = (w[i]>>7)&0xFF; s += fabsf((float)e - 120.f); }
    __shared__ float red[4];
    for (int o=32;o>0;o>>=1) s += __shfl_down(s,o,64);
    int wv=t>>6, lane=t&63;
    if (lane==0) red[wv]=s;
    __syncthreads();
    if (t==0) flag[0] = ((red[0]+red[1]+red[2]+red[3]) * (1.f/4096.f) > 20.f) ? 1 : 0;
}

__global__ void zero_u32_k(unsigned int* p, long n){
    long i = (long)blockIdx.x*256 + threadIdx.x;
    if (i < n) p[i] = 0u;
}

// ---------------- topic memory ----------------
// writes softmax rows as bf16 into wdb [64][VBP_N] (rows 50..63 and cols >=VB_N pre-zeroed)
__global__ __launch_bounds__(256) void softmax_wdec_k(
    const void* __restrict__ Wd, const void* __restrict__ bd, bf16* __restrict__ wdb,
    const int* __restrict__ flagp)
{
    const int isf = *flagp;
    int r = blockIdx.x, t = threadIdx.x;
    __shared__ float red[4];
    float mx = -1e30f;
    for (int c=t;c<VB_N;c+=256) mx = fmaxf(mx, ldw(Wd,(long)r*VB_N+c,isf) + ldw(bd,c,isf));
    for (int o=32;o>0;o>>=1) mx = fmaxf(mx, __shfl_down(mx,o,64));
    int w=t>>6, lane=t&63;
    if (lane==0) red[w]=mx;
    __syncthreads();
    mx = fmaxf(fmaxf(red[0],red[1]),fmaxf(red[2],red[3]));
    __syncthreads();
    float sm=0.f;
    for (int c=t;c<VB_N;c+=256) sm += __expf(ldw(Wd,(long)r*VB_N+c,isf) + ldw(bd,c,isf) - mx);
    for (int o=32;o>0;o>>=1) sm += __shfl_down(sm,o,64);
    if (lane==0) red[w]=sm;
    __syncthreads();
    float inv = 1.f/(red[0]+red[1]+red[2]+red[3]);
    for (int c=t;c<VB_N;c+=256)
        wdb[(long)r*VBP_N + c] = f2b(__expf(ldw(Wd,(long)r*VB_N+c,isf) + ldw(bd,c,isf) - mx)*inv);
}

// hrel[64][1024] bf16 = relu(hmem + b1), rows >= T_N zeroed
__global__ __launch_bounds__(256) void relu_bias_k(
    const float* __restrict__ hmem, const void* __restrict__ b1,
    bf16* __restrict__ hrel, const int* __restrict__ flagp)
{
    const int isf = *flagp;
    int r = blockIdx.x, t = threadIdx.x;
    for (int c=t;c<1024;c+=256){
        float v = (r < T_N) ? fmaxf(hmem[r*1024+c] + ldw(b1,c,isf), 0.f) : 0.f;
        hrel[r*1024+c] = f2b(v);
    }
}

// plain LN over 50 rows of fcout[64][512] (bias b2 already added in GEMM epilogue)
__global__ __launch_bounds__(256) void ln_topic_k(
    const float* __restrict__ fcout,
    const void* __restrict__ lg, const void* __restrict__ lb,
    float* __restrict__ tmf, bf16* __restrict__ tmb, const int* __restrict__ flagp)
{
    const int isf = *flagp;
    int r = blockIdx.x, t = threadIdx.x;
    float a0 = fcout[r*512+t], a1 = fcout[r*512+t+256];
    __shared__ float red[4];
    float s = a0 + a1;
    for (int o=32;o>0;o>>=1) s += __shfl_down(s,o,64);
    int w=t>>6, lane=t&63;
    if (lane==0) red[w]=s;
    __syncthreads();
    float mean = (red[0]+red[1]+red[2]+red[3]) * (1.f/512.f);
    float d0=a0-mean, d1=a1-mean;
    float q = d0*d0 + d1*d1;
    __syncthreads();
    for (int o=32;o>0;o>>=1) q += __shfl_down(q,o,64);
    if (lane==0) red[w]=q;
    __syncthreads();
    float var = (red[0]+red[1]+red[2]+red[3]) * (1.f/512.f);
    float rstd = rsqrtf(var + 1e-12f);
    float o0 = d0*rstd*ldw(lg,t,isf) + ldw(lb,t,isf);
    float o1 = d1*rstd*ldw(lg,t+256,isf) + ldw(lb,t+256,isf);
    tmf[r*512+t]=o0; tmf[r*512+t+256]=o1;
    tmb[r*512+t]=f2b(o0); tmb[r*512+t+256]=f2b(o1);
}

// ---------------- embedding + ragged insert ----------------
__global__ __launch_bounds__(256) void embed_insert_k(
    const int* __restrict__ ids, const int* __restrict__ lens,
    const void* __restrict__ embed, const float* __restrict__ tmf,
    const bf16* __restrict__ tmb, float* __restrict__ hf, bf16* __restrict__ hb,
    const int* __restrict__ flagp)
{
    const int isf = *flagp;
    int j = blockIdx.x, b = blockIdx.y, t = threadIdx.x;
    int L = lens[b]; L = L<1?1:(L>S_N?S_N:L);
    long orow = ((long)b*ST_N + j)*512;
    if (j >= L && j < L + T_N) {
        int m = j - L;
        for (int c=t;c<512;c+=256){ float v = tmf[m*512+c]; hf[orow+c]=v; hb[orow+c]=tmb[m*512+c]; }
    } else {
        int sj = (j < L) ? j : j - T_N;   // in [0, 511]
        int id = ids[b*S_N + sj];
        for (int c=t;c<512;c+=256){ float e = ldw(embed,(long)id*512+c,isf); hf[orow+c]=e; hb[orow+c]=f2b(e); }
    }
}

// ---------------- weight prep ----------------
// dst[z*dstride + (n0+n)*R + (k0+k)] = src[z*sstride + min(k0+k,Ksrc-1)*C + (n0+n)]
__global__ __launch_bounds__(256) void transpose_k(
    const void* __restrict__ src, bf16* __restrict__ dst,
    int R, int C, long sstride, long dstride, int Ksrc, const int* __restrict__ flagp)
{
    const int isf = *flagp;
    __shared__ bf16 tile[32][33];
    int n0 = blockIdx.x * 32, k0 = blockIdx.y * 32, z = blockIdx.z;
    int t = threadIdx.x;
    int nl = t & 31, kb = t >> 5;
    #pragma unroll
    for (int i=0;i<4;i++) {
        int k = k0 + kb + i*8; k = k < Ksrc ? k : Ksrc-1;
        tile[kb+i*8][nl] = f2b(ldw(src, z*sstride + (long)k*C + n0+nl, isf));
    }
    __syncthreads();
    int kl = t & 31, nb = t >> 5;
    #pragma unroll
    for (int i=0;i<4;i++) {
        int n = nb + i*8;
        dst[z*dstride + (long)(n0+n)*R + k0+kl] = tile[kl][n];
    }
}

__global__ void concat_bias_k(const void* bq, const void* bk, const void* bv, bf16* out,
                              const int* __restrict__ flagp){
    const int isf = *flagp;
    int i = blockIdx.x*256 + threadIdx.x;
    if (i >= NL_N*1536) return;
    int l = i/1536, n = i%1536;
    float v = (n<512) ? ldw(bq,l*512+n,isf) : (n<1024 ? ldw(bk,l*512+n-512,isf) : ldw(bv,l*512+n-1024,isf));
    out[i] = f2b(v);
}

// Vt[z][n][k]: n = head dim (64), k = key (576, zero pad k>=562); z = b*8+h over all 256
__global__ __launch_bounds__(256) void transpose_v_k(
    const bf16* __restrict__ qkv, bf16* __restrict__ Vt)
{
    __shared__ bf16 tl[64*33];
    int k0 = blockIdx.x * 32, z = blockIdx.z;
    int b = z >> 3, h = z & 7;
    int t = threadIdx.x;
    int n = t & 63, kb = t >> 6;
    #pragma unroll
    for (int i=0;i<8;i++) {
        int kl = kb + 4*i;
        int kg = k0 + kl;
        bf16 v = (kg < ST_N) ? qkv[((long)(b*ST_N + kg))*1536 + 1024 + h*64 + n] : f2b(0.f);
        tl[n*33 + kl] = v;
    }
    __syncthreads();
    int kk = t & 31, nb = t >> 5;
    #pragma unroll
    for (int i=0;i<8;i++) {
        int nn = nb + 8*i;
        Vt[((long)z*64 + nn)*STP_N + k0 + kk] = tl[nn*33 + kk];
    }
}

// ---------------- MFMA GEMM: C = A[M,K] @ Bt[N,K]^T ----------------
constexpr int EPI_BF16=0, EPI_F32=1, EPI_GELU=2, EPI_ATOMIC=3;

template<int BM, int BN, int MODE>
__global__ __launch_bounds__(256,2) void gemm_k(
    const bf16* __restrict__ Ag, const bf16* __restrict__ Bg, void* __restrict__ Cg,
    const void* __restrict__ bias, long bias_off,
    int M, int N, int K, int lda, int ldb, int ldc, int Nst, int kch,
    const int* __restrict__ flagp)
{
    const int isf = *flagp;
    __shared__ bf16 lA[BM*32];
    __shared__ bf16 lB[BN*32];
    const int tid = threadIdx.x;
    const int tile_m = blockIdx.y * BM;
    const int tile_n = blockIdx.x * BN;

    bf16*  C16 = (bf16*)Cg;
    float* C32 = (float*)Cg;

    constexpr int WM = BM/2, WN = BN/2, MI = WM/16, NI = WN/16;
    const int w = tid>>6, lane = tid&63;
    const int wm = w>>1, wn = w&1;
    const int quad = lane>>4, lrow = lane&15;

    f32x4 zero = {0.f,0.f,0.f,0.f};
    f32x4 acc[MI][NI];
    #pragma unroll
    for (int i=0;i<MI;i++)
        #pragma unroll
        for (int j=0;j<NI;j++) acc[i][j] = zero;

    int ks = 0, ke = K;
    if (kch > 0) { ks = blockIdx.z * kch; ke = ks + kch; if (ke > K) ke = K; }

    for (int k0=ks;k0<ke;k0+=32) {
        __syncthreads();
        #pragma unroll
        for (int r=0;r<BM/64;r++) {
            int e = (r*256 + tid)*8;
            int row = e>>5, kk = e&31;
            int gr = tile_m + row; gr = gr < M ? gr : M-1;
            load_lds16(Ag + (long)gr*lda + k0 + kk, &lA[e]);
        }
        #pragma unroll
        for (int r=0;r<BN/64;r++) {
            int e = (r*256 + tid)*8;
            int row = e>>5, kk = e&31;
            int gr = tile_n + row; gr = gr < N ? gr : N-1;
            load_lds16(Bg + (long)gr*ldb + k0 + kk, &lB[e]);
        }
        __syncthreads();
        short8 afr[MI], bfr[NI];
        #pragma unroll
        for (int i=0;i<MI;i++) afr[i] = *(const short8*)&lA[(wm*WM + i*16 + lrow)*32 + quad*8];
        #pragma unroll
        for (int j=0;j<NI;j++) bfr[j] = *(const short8*)&lB[(wn*WN + j*16 + lrow)*32 + quad*8];
        #pragma unroll
        for (int i=0;i<MI;i++)
            #pragma unroll
            for (int j=0;j<NI;j++)
                acc[i][j] = __builtin_amdgcn_mfma_f32_16x16x32_bf16(afr[i], bfr[j], acc[i][j], 0, 0, 0);
    }

    #pragma unroll
    for (int i=0;i<MI;i++) {
        #pragma unroll
        for (int j=0;j<NI;j++) {
            int col = tile_n + wn*WN + j*16 + lrow;
            int rb  = tile_m + wm*WM + i*16 + quad*4;
            #pragma unroll
            for (int r=0;r<4;r++) {
                int row = rb + r;
                if (row >= M || col >= Nst) continue;
                float v = acc[i][j][r];
                if constexpr (MODE == EPI_BF16) {
                    C16[(long)row*ldc + col] = f2b(v + b2f(((const bf16*)bias)[bias_off + col]));
                } else if constexpr (MODE == EPI_F32) {
                    C32[(long)row*ldc + col] = v + ldw(bias, bias_off + col, isf);
                } else if constexpr (MODE == EPI_GELU) {
                    float x = v + ldw(bias, bias_off + col, isf);
                    C16[(long)row*ldc + col] = f2b(0.5f*x*(1.f + erff(x*0.70710678118654752f)));
                } else { // EPI_ATOMIC
                    atomicAdd(&C32[(long)row*ldc + col], v);
                }
            }
        }
    }
}

// ---------------- flash attention ----------------
// grid: x = q-tile (0..4), z = b*8+h (0..255). 256 threads = 4 waves, wave owns 32 q rows.
// LDS rows are 64 bf16 with XOR-swizzled 8-elem chunks: chunk' = chunk ^ (row&7).
__global__ __launch_bounds__(256,2) void flash_k(
    const bf16* __restrict__ qkv, const bf16* __restrict__ Vt,
    bf16* __restrict__ ctx, const int* __restrict__ slens)
{
    __shared__ __align__(16) bf16 lQ[128*64];
    __shared__ __align__(16) bf16 lK[64*64];
    __shared__ __align__(16) bf16 lV[64*64];
    __shared__ __align__(16) bf16 lP[128*64];
    const int z = blockIdx.z, b = z>>3, h = z&7;
    const int qt = blockIdx.x;
    const int tid = threadIdx.x;
    const int w = tid>>6, lane = tid&63;
    const int quad = lane>>4, l15 = lane&15;
    int L = slens[b]; L = L<1?1:(L>S_N?S_N:L);
    const int lenT = L + T_N;

    // stage Q once (swizzled source chunk keeps LDS dest contiguous)
    #pragma unroll
    for (int rr=0;rr<4;rr++){
        int ci = rr*256 + tid;
        int row = ci>>3, c8 = (ci&7) ^ (row&7);
        int gr = qt*128 + row; gr = gr < ST_N ? gr : ST_N-1;
        load_lds16(qkv + ((long)(b*ST_N+gr))*1536 + h*64 + c8*8, &lQ[ci*8]);
    }

    f32x4 zerov = {0.f,0.f,0.f,0.f};
    f32x4 O[2][4];
    float m_i[2][4], l_i[2][4];
    #pragma unroll
    for (int i=0;i<2;i++){
        #pragma unroll
        for (int j=0;j<4;j++) O[i][j] = zerov;
        #pragma unroll
        for (int r=0;r<4;r++){ m_i[i][r]=-1e30f; l_i[i][r]=0.f; }
    }

    for (int kt=0; kt<9; kt++){
        __syncthreads();   // protect lK/lV/lP from prior-iter readers
        #pragma unroll
        for (int rr=0;rr<2;rr++){
            int ci = rr*256+tid;
            int row = ci>>3, c8 = (ci&7) ^ (row&7);
            int kr = kt*64+row; kr = kr < ST_N ? kr : ST_N-1;
            load_lds16(qkv + ((long)(b*ST_N+kr))*1536 + 512 + h*64 + c8*8, &lK[ci*8]);
        }
        #pragma unroll
        for (int rr=0;rr<2;rr++){
            int ci = rr*256+tid;
            int n = ci>>3, c8 = (ci&7) ^ (n&7);
            load_lds16(Vt + ((long)z*64+n)*STP_N + kt*64 + c8*8, &lV[ci*8]);
        }
        __syncthreads();

        // S = Q @ K^T  (S rows: quad*4+reg; cols: l15)
        f32x4 S[2][4];
        #pragma unroll
        for (int i=0;i<2;i++)
            #pragma unroll
            for (int j=0;j<4;j++) S[i][j] = zerov;
        #pragma unroll
        for (int kc=0;kc<2;kc++){
            short8 aQ[2], bK[4];
            #pragma unroll
            for (int i=0;i<2;i++){
                int row = w*32+i*16+l15;
                aQ[i] = *(const short8*)&lQ[row*64 + (((kc*4+quad) ^ (row&7))<<3)];
            }
            #pragma unroll
            for (int j=0;j<4;j++){
                int row = j*16+l15;
                bK[j] = *(const short8*)&lK[row*64 + (((kc*4+quad) ^ (row&7))<<3)];
            }
            #pragma unroll
            for (int i=0;i<2;i++)
                #pragma unroll
                for (int j=0;j<4;j++)
                    S[i][j] = __builtin_amdgcn_mfma_f32_16x16x32_bf16(aQ[i], bK[j], S[i][j], 0,0,0);
        }

        // scale + mask + online softmax stats
        #pragma unroll
        for (int i=0;i<2;i++){
            #pragma unroll
            for (int r=0;r<4;r++){
                float mx = -1e30f;
                #pragma unroll
                for (int j=0;j<4;j++){
                    int col = kt*64 + j*16 + l15;
                    float s = S[i][j][r]*0.125f + (col < lenT ? 0.f : -10000.f);
                    S[i][j][r] = s;
                    mx = fmaxf(mx, s);
                }
                #pragma unroll
                for (int o=1;o<16;o<<=1) mx = fmaxf(mx, __shfl_xor(mx, o, 64));
                float mn = fmaxf(m_i[i][r], mx);
                float alpha = __expf(m_i[i][r] - mn);
                m_i[i][r] = mn;
                float sm = 0.f;
                #pragma unroll
                for (int j=0;j<4;j++){
                    float pv = __expf(S[i][j][r] - mn);
                    S[i][j][r] = pv;
                    sm += pv;
                }
                #pragma unroll
                for (int o=1;o<16;o<<=1) sm += __shfl_xor(sm, o, 64);
                l_i[i][r] = l_i[i][r]*alpha + sm;
                #pragma unroll
                for (int j=0;j<4;j++) O[i][j][r] *= alpha;
            }
        }

        // P (C-layout) -> LDS (A-layout read next), swizzled
        #pragma unroll
        for (int i=0;i<2;i++)
            #pragma unroll
            for (int j=0;j<4;j++)
                #pragma unroll
                for (int r=0;r<4;r++){
                    int row = w*32 + i*16 + quad*4 + r;
                    int col = j*16 + l15;
                    lP[row*64 + (((col>>3) ^ (row&7))<<3) + (col&7)] = f2b(S[i][j][r]);
                }
        __syncthreads();

        // O += P @ V
        #pragma unroll
        for (int kc=0;kc<2;kc++){
            short8 aP[2], bV[4];
            #pragma unroll
            for (int i=0;i<2;i++){
                int row = w*32+i*16+l15;
                aP[i] = *(const short8*)&lP[row*64 + (((kc*4+quad) ^ (row&7))<<3)];
            }
            #pragma unroll
            for (int j=0;j<4;j++){
                int row = j*16+l15;
                bV[j] = *(const short8*)&lV[row*64 + (((kc*4+quad) ^ (row&7))<<3)];
            }
            #pragma unroll
            for (int i=0;i<2;i++)
                #pragma unroll
                for (int j=0;j<4;j++)
                    O[i][j] = __builtin_amdgcn_mfma_f32_16x16x32_bf16(aP[i], bV[j], O[i][j], 0,0,0);
        }
    }

    #pragma unroll
    for (int i=0;i<2;i++)
        #pragma unroll
        for (int j=0;j<4;j++)
            #pragma unroll
            for (int r=0;r<4;r++){
                int row = qt*128 + w*32 + i*16 + quad*4 + r;
                if (row < ST_N)
                    ctx[((long)(b*ST_N+row))*512 + h*64 + j*16 + l15] = f2b(O[i][j][r] / l_i[i][r]);
            }
}

// ---------------- residual + LN (fp32 state + bf16 shadow) ----------------
__global__ __launch_bounds__(256) void ln_residual_k(
    const float* __restrict__ tmp, float* __restrict__ hf, bf16* __restrict__ hb,
    const void* __restrict__ g, const void* __restrict__ bb, long goff,
    void* __restrict__ outp, int is_final, const int* __restrict__ flagp)
{
    const int isf = *flagp;
    const int of32 = is_final && isf;
    long base = (long)blockIdx.x * 512;
    int t = threadIdx.x;
    float v0 = hf[base+t]     + tmp[base+t];
    float v1 = hf[base+t+256] + tmp[base+t+256];
    __shared__ float red[4];
    float s = v0+v1;
    for (int o=32;o>0;o>>=1) s += __shfl_down(s,o,64);
    int w=t>>6, lane=t&63;
    if (lane==0) red[w]=s;
    __syncthreads();
    float mean = (red[0]+red[1]+red[2]+red[3]) * (1.f/512.f);
    float d0=v0-mean, d1=v1-mean;
    float q = d0*d0 + d1*d1;
    __syncthreads();
    for (int o=32;o>0;o>>=1) q += __shfl_down(q,o,64);
    if (lane==0) red[w]=q;
    __syncthreads();
    float var = (red[0]+red[1]+red[2]+red[3]) * (1.f/512.f);
    float rstd = rsqrtf(var + 1e-12f);
    float o0 = d0*rstd*ldw(g,goff+t,isf) + ldw(bb,goff+t,isf);
    float o1 = d1*rstd*ldw(g,goff+t+256,isf) + ldw(bb,goff+t+256,isf);
    hf[base+t]=o0; hf[base+t+256]=o1;
    hb[base+t]=f2b(o0); hb[base+t+256]=f2b(o1);
    if (of32) {
        ((float*)outp)[base+t]=o0; ((float*)outp)[base+t+256]=o1;
    } else {
        ((bf16*)outp)[base+t]=f2b(o0); ((bf16*)outp)[base+t+256]=f2b(o1);
    }
}

extern "C" void kernel_launch(void* const* d_in, const int* in_sizes, int n_in,
                              void* d_out, int out_size, void* d_ws, size_t ws_size,
                              hipStream_t stream)
{
    (void)in_sizes; (void)n_in; (void)out_size; (void)ws_size;
    const int*  ids   = (const int*) d_in[0];
    const int*  slens = (const int*) d_in[1];
    const void* embed = d_in[2];
    const void* Wdec  = d_in[3];
    const void* bdec  = d_in[4];
    const void* mW1   = d_in[5];
    const void* mb1   = d_in[6];
    const void* mW2   = d_in[7];
    const void* mb2   = d_in[8];
    const void* mlg   = d_in[9];
    const void* mlb   = d_in[10];
    const void* Wq    = d_in[11];
    const void* bq    = d_in[12];
    const void* Wk    = d_in[13];
    const void* bk    = d_in[14];
    const void* Wv    = d_in[15];
    const void* bv    = d_in[16];
    const void* Wo    = d_in[17];
    const void* bo    = d_in[18];
    const void* l1g   = d_in[19];
    const void* l1b   = d_in[20];
    const void* Wi    = d_in[21];
    const void* bi    = d_in[22];
    const void* Wf    = d_in[23];
    const void* bfv   = d_in[24];
    const void* l2g   = d_in[25];
    const void* l2b   = d_in[26];

    char* p = (char*)d_ws;
    auto alloc = [&](size_t bytes)->void* {
        void* r = (void*)p; p += (bytes + 255) & ~(size_t)255; return r; };
    int*   flag  = (int*)  alloc(256);
    float* tmf   = (float*)alloc((size_t)T_N*512*4);
    bf16*  tmb   = (bf16*) alloc((size_t)T_N*512*2);
    float* hmem  = (float*)alloc((size_t)64*1024*4);
    bf16*  hrel  = (bf16*) alloc((size_t)64*1024*2);
    float* fcout = (float*)alloc((size_t)64*512*4);
    float* hidf  = (float*)alloc((size_t)NTOK_N*512*4);
    bf16*  hidb  = (bf16*) alloc((size_t)NTOK_N*512*2);
    bf16*  qkvt  = (bf16*) alloc((size_t)NL_N*1536*512*2);
    bf16*  wot   = (bf16*) alloc((size_t)NL_N*512*512*2);
    bf16*  wit   = (bf16*) alloc((size_t)NL_N*2048*512*2);
    bf16*  wft   = (bf16*) alloc((size_t)NL_N*512*2048*2);
    bf16*  bqkv  = (bf16*) alloc((size_t)NL_N*1536*2);
    // R1 union (time-disjoint): prelude [wdb 3.84M | W1t 61.5M | W2t 1M] <-> [qkv 55.25M] <-> [ffb 73.66M]
    char*  R1    = (char*) alloc((size_t)NTOK_N*2048*2);
    bf16*  wdb   = (bf16*)R1;
    bf16*  W1t   = (bf16*)(R1 + (size_t)64*VBP_N*2);
    bf16*  W2t   = (bf16*)(R1 + (size_t)64*VBP_N*2 + (size_t)1024*VBP_N*2);
    bf16*  qkv   = (bf16*)R1;
    bf16*  ffb   = (bf16*)R1;
    // RU2: ctx (18.42M) + [Vt 18.87M <-> tmpb 36.83M]
    bf16*  ctx   = (bf16*) alloc((size_t)NTOK_N*512*2);
    char*  RU2   = (char*) alloc((size_t)NTOK_N*512*4);
    bf16*  Vt    = (bf16*)RU2;
    float* tmpb  = (float*)RU2;
    // total ~= 210 MB

    detect_k<<<1,256,0,stream>>>((const unsigned int*)embed, flag);

    // topic memory: softmax -> FC1 (MFMA, K-split atomic) -> relu -> FC2 (MFMA) -> LN
    zero_u32_k<<<((64L*VBP_N/2)+255)/256,256,0,stream>>>((unsigned int*)wdb, 64L*VBP_N/2);
    zero_u32_k<<<((64L*1024)+255)/256,256,0,stream>>>((unsigned int*)hmem, 64L*1024);
    softmax_wdec_k<<<T_N,256,0,stream>>>(Wdec,bdec,wdb,flag);
    // W1t[n][k] = W1[k][n], n<1024, k<30016 (clamped)
    transpose_k<<<dim3(32,VBP_N/32,1),256,0,stream>>>(mW1, W1t, VBP_N, 1024, 0L, 0L, VB_N, flag);
    // W2t[n][k] = W2[k][n], n<512, k<1024
    transpose_k<<<dim3(16,32,1),256,0,stream>>>(mW2, W2t, 1024, 512, 0L, 0L, 1024, flag);
    gemm_k<64,128,EPI_ATOMIC><<<dim3(8,1,32),256,0,stream>>>(
        wdb, W1t, hmem, nullptr, 0,
        64, 1024, VBP_N, VBP_N, VBP_N, 1024, 1024, 960, flag);
    relu_bias_k<<<64,256,0,stream>>>(hmem, mb1, hrel, flag);
    gemm_k<64,128,EPI_F32><<<dim3(4,1,1),256,0,stream>>>(
        hrel, W2t, fcout, mb2, 0,
        64, 512, 1024, 1024, 1024, 512, 512, 0, flag);
    ln_topic_k<<<T_N,256,0,stream>>>(fcout, mlg, mlb, tmf, tmb, flag);
    embed_insert_k<<<dim3(ST_N,B_N),256,0,stream>>>(ids, slens, embed, tmf, tmb, hidf, hidb, flag);

    // weight prep (canonical bf16, [N][K] layouts)
    transpose_k<<<dim3(16,16,NL_N),256,0,stream>>>(Wq, qkvt,          512, 512, 262144L, 786432L, 512, flag);
    transpose_k<<<dim3(16,16,NL_N),256,0,stream>>>(Wk, qkvt+262144,   512, 512, 262144L, 786432L, 512, flag);
    transpose_k<<<dim3(16,16,NL_N),256,0,stream>>>(Wv, qkvt+524288,   512, 512, 262144L, 786432L, 512, flag);
    transpose_k<<<dim3(16,16,NL_N),256,0,stream>>>(Wo, wot,           512, 512, 262144L, 262144L, 512, flag);
    transpose_k<<<dim3(64,16,NL_N),256,0,stream>>>(Wi, wit,           512, 2048, 1048576L, 1048576L, 512, flag);
    transpose_k<<<dim3(16,64,NL_N),256,0,stream>>>(Wf, wft,           2048, 512, 1048576L, 1048576L, 2048, flag);
    concat_bias_k<<<(NL_N*1536+255)/256,256,0,stream>>>(bq,bk,bv,bqkv,flag);

    for (int l=0;l<NL_N;l++) {
        gemm_k<128,128,EPI_BF16><<<dim3(12,141,1),256,0,stream>>>(
            hidb, qkvt + (size_t)l*786432, qkv, bqkv, (long)l*1536,
            NTOK_N, 1536, 512, 512, 512, 1536, 1536, 0, flag);
        transpose_v_k<<<dim3(18,1,256),256,0,stream>>>(qkv, Vt);
        flash_k<<<dim3(5,1,256),256,0,stream>>>(qkv, Vt, ctx, slens);
        gemm_k<128,128,EPI_F32><<<dim3(4,141,1),256,0,stream>>>(
            ctx, wot + (size_t)l*262144, tmpb, bo, (long)l*512,
            NTOK_N, 512, 512, 512, 512, 512, 512, 0, flag);
        ln_residual_k<<<NTOK_N,256,0,stream>>>(tmpb, hidf, hidb, l1g, l1b, (long)l*512,
                                               hidb, 0, flag);
        gemm_k<128,128,EPI_GELU><<<dim3(16,141,1),256,0,stream>>>(
            hidb, wit + (size_t)l*1048576, ffb, bi, (long)l*2048,
            NTOK_N, 2048, 512, 512, 512, 2048, 2048, 0, flag);
        gemm_k<128,128,EPI_F32><<<dim3(4,141,1),256,0,stream>>>(
            ffb, wft + (size_t)l*1048576, tmpb, bfv, (long)l*512,
            NTOK_N, 512, 2048, 2048, 2048, 512, 512, 0, flag);
        ln_residual_k<<<NTOK_N,256,0,stream>>>(tmpb, hidf, hidb, l2g, l2b, (long)l*512,
                                               (l == NL_N-1) ? d_out : (void*)hidb,
                                               (l == NL_N-1) ? 1 : 0, flag);
    }
}

// Round 5
// 1977.184 us; speedup vs baseline: 1.9952x; 1.0460x over previous
//
#include <hip/hip_runtime.h>
#include <hip/hip_bf16.h>
#include <math.h>

using bf16 = __hip_bfloat16;
typedef __attribute__((ext_vector_type(4))) float f32x4;
typedef __attribute__((ext_vector_type(8))) short short8;

#define B_N 32
#define S_N 512
#define T_N 50
#define H_N 8
#define NL_N 4
#define VB_N 30000
#define VBP_N 30016          // VB padded to mult of 32
#define ST_N 562
#define STP_N 576
#define NTOK_N (B_N*ST_N)   // 17984
#define WCH_N 16             // softmax_wdec column chunks
#define WCW_N 1875           // 30000/16

__device__ __forceinline__ float b2f(bf16 x){ return __bfloat162float(x); }
__device__ __forceinline__ bf16  f2b(float x){ return __float2bfloat16(x); }
// flag-aware raw-input load: f==1 -> buffer is float32, else bf16
__device__ __forceinline__ float ldw(const void* p, long i, int f){
    return f ? ((const float*)p)[i] : __bfloat162float(((const bf16*)p)[i]);
}

__device__ __forceinline__ void load_lds16(const void* g, void* l){
    __builtin_amdgcn_global_load_lds((const __attribute__((address_space(1))) void*)g,
                                     (__attribute__((address_space(3))) void*)l, 16, 0, 0);
}

__device__ __forceinline__ float block_reduce_max(float v, float* red, int t){
    for (int o=32;o>0;o>>=1) v = fmaxf(v, __shfl_down(v,o,64));
    int w=t>>6, lane=t&63;
    if (lane==0) red[w]=v;
    __syncthreads();
    return fmaxf(fmaxf(red[0],red[1]),fmaxf(red[2],red[3]));
}
__device__ __forceinline__ float block_reduce_sum(float v, float* red, int t){
    for (int o=32;o>0;o>>=1) v += __shfl_down(v,o,64);
    int w=t>>6, lane=t&63;
    if (lane==0) red[w]=v;
    __syncthreads();
    return red[0]+red[1]+red[2]+red[3];
}

// ---------------- dtype detector ----------------
__global__ __launch_bounds__(256) void detect_k(const unsigned int* __restrict__ w, int* flag)
{
    int t = threadIdx.x;
    float s = 0.f;
    for (int i=t;i<4096;i+=256){ int e = (w[i]>>7)&0xFF; s += fabsf((float)e - 120.f); }
    __shared__ float red[4];
    for (int o=32;o>0;o>>=1) s += __shfl_down(s,o,64);
    int wv=t>>6, lane=t&63;
    if (lane==0) red[wv]=s;
    __syncthreads();
    if (t==0) flag[0] = ((red[0]+red[1]+red[2]+red[3]) * (1.f/4096.f) > 20.f) ? 1 : 0;
}

__global__ void zero_u32_k(unsigned int* p, long n){
    long i = (long)blockIdx.x*256 + threadIdx.x;
    if (i < n) p[i] = 0u;
}

// ---------------- topic memory: parallel W_dec softmax ----------------
// grid (WCH_N, T_N): partial max per (row, chunk)
__global__ __launch_bounds__(256) void wd_partmax_k(
    const void* __restrict__ Wd, const void* __restrict__ bd,
    float* __restrict__ pmax, const int* __restrict__ flagp)
{
    const int isf = *flagp;
    int ch = blockIdx.x, r = blockIdx.y, t = threadIdx.x;
    int c0 = ch*WCW_N, c1 = c0 + WCW_N;
    __shared__ float red[4];
    float mx = -1e30f;
    for (int c=c0+t;c<c1;c+=256) mx = fmaxf(mx, ldw(Wd,(long)r*VB_N+c,isf) + ldw(bd,c,isf));
    mx = block_reduce_max(mx, red, t);
    if (t==0) pmax[r*WCH_N + ch] = mx;
}

__global__ __launch_bounds__(256) void wd_partsum_k(
    const void* __restrict__ Wd, const void* __restrict__ bd,
    const float* __restrict__ pmax, float* __restrict__ psum, const int* __restrict__ flagp)
{
    const int isf = *flagp;
    int ch = blockIdx.x, r = blockIdx.y, t = threadIdx.x;
    float mx = -1e30f;
    #pragma unroll
    for (int i=0;i<WCH_N;i++) mx = fmaxf(mx, pmax[r*WCH_N+i]);
    int c0 = ch*WCW_N, c1 = c0 + WCW_N;
    __shared__ float red[4];
    float sm = 0.f;
    for (int c=c0+t;c<c1;c+=256) sm += __expf(ldw(Wd,(long)r*VB_N+c,isf) + ldw(bd,c,isf) - mx);
    sm = block_reduce_sum(sm, red, t);
    if (t==0) psum[r*WCH_N + ch] = sm;
}

__global__ __launch_bounds__(256) void wd_write_k(
    const void* __restrict__ Wd, const void* __restrict__ bd,
    const float* __restrict__ pmax, const float* __restrict__ psum,
    bf16* __restrict__ wdb, const int* __restrict__ flagp)
{
    const int isf = *flagp;
    int ch = blockIdx.x, r = blockIdx.y, t = threadIdx.x;
    float mx = -1e30f, sm = 0.f;
    #pragma unroll
    for (int i=0;i<WCH_N;i++){ mx = fmaxf(mx, pmax[r*WCH_N+i]); sm += psum[r*WCH_N+i]; }
    float inv = 1.f/sm;
    int c0 = ch*WCW_N, c1 = c0 + WCW_N;
    for (int c=c0+t;c<c1;c+=256)
        wdb[(long)r*VBP_N + c] = f2b(__expf(ldw(Wd,(long)r*VB_N+c,isf) + ldw(bd,c,isf) - mx)*inv);
}

// hrel[64][1024] bf16 = relu(hmem + b1), rows >= T_N zeroed
__global__ __launch_bounds__(256) void relu_bias_k(
    const float* __restrict__ hmem, const void* __restrict__ b1,
    bf16* __restrict__ hrel, const int* __restrict__ flagp)
{
    const int isf = *flagp;
    int r = blockIdx.x, t = threadIdx.x;
    for (int c=t;c<1024;c+=256){
        float v = (r < T_N) ? fmaxf(hmem[r*1024+c] + ldw(b1,c,isf), 0.f) : 0.f;
        hrel[r*1024+c] = f2b(v);
    }
}

// plain LN over 50 rows of fcout[64][512] (bias b2 already added in GEMM epilogue)
__global__ __launch_bounds__(256) void ln_topic_k(
    const float* __restrict__ fcout,
    const void* __restrict__ lg, const void* __restrict__ lb,
    float* __restrict__ tmf, bf16* __restrict__ tmb, const int* __restrict__ flagp)
{
    const int isf = *flagp;
    int r = blockIdx.x, t = threadIdx.x;
    float a0 = fcout[r*512+t], a1 = fcout[r*512+t+256];
    __shared__ float red[4];
    float mean = block_reduce_sum(a0+a1, red, t) * (1.f/512.f);
    float d0=a0-mean, d1=a1-mean;
    __syncthreads();
    float var = block_reduce_sum(d0*d0+d1*d1, red, t) * (1.f/512.f);
    float rstd = rsqrtf(var + 1e-12f);
    float o0 = d0*rstd*ldw(lg,t,isf) + ldw(lb,t,isf);
    float o1 = d1*rstd*ldw(lg,t+256,isf) + ldw(lb,t+256,isf);
    tmf[r*512+t]=o0; tmf[r*512+t+256]=o1;
    tmb[r*512+t]=f2b(o0); tmb[r*512+t+256]=f2b(o1);
}

// ---------------- embedding + ragged insert ----------------
__global__ __launch_bounds__(256) void embed_insert_k(
    const int* __restrict__ ids, const int* __restrict__ lens,
    const void* __restrict__ embed, const float* __restrict__ tmf,
    const bf16* __restrict__ tmb, float* __restrict__ hf, bf16* __restrict__ hb,
    const int* __restrict__ flagp)
{
    const int isf = *flagp;
    int j = blockIdx.x, b = blockIdx.y, t = threadIdx.x;
    int L = lens[b]; L = L<1?1:(L>S_N?S_N:L);
    long orow = ((long)b*ST_N + j)*512;
    if (j >= L && j < L + T_N) {
        int m = j - L;
        for (int c=t;c<512;c+=256){ float v = tmf[m*512+c]; hf[orow+c]=v; hb[orow+c]=tmb[m*512+c]; }
    } else {
        int sj = (j < L) ? j : j - T_N;   // in [0, 511]
        int id = ids[b*S_N + sj];
        for (int c=t;c<512;c+=256){ float e = ldw(embed,(long)id*512+c,isf); hf[orow+c]=e; hb[orow+c]=f2b(e); }
    }
}

// ---------------- weight prep ----------------
// dst[z*dstride + (n0+n)*R + (k0+k)] = src[z*sstride + min(k0+k,Ksrc-1)*C + (n0+n)]
__global__ __launch_bounds__(256) void transpose_k(
    const void* __restrict__ src, bf16* __restrict__ dst,
    int R, int C, long sstride, long dstride, int Ksrc, const int* __restrict__ flagp)
{
    const int isf = *flagp;
    __shared__ bf16 tile[32][33];
    int n0 = blockIdx.x * 32, k0 = blockIdx.y * 32, z = blockIdx.z;
    int t = threadIdx.x;
    int nl = t & 31, kb = t >> 5;
    #pragma unroll
    for (int i=0;i<4;i++) {
        int k = k0 + kb + i*8; k = k < Ksrc ? k : Ksrc-1;
        tile[kb+i*8][nl] = f2b(ldw(src, z*sstride + (long)k*C + n0+nl, isf));
    }
    __syncthreads();
    int kl = t & 31, nb = t >> 5;
    #pragma unroll
    for (int i=0;i<4;i++) {
        int n = nb + i*8;
        dst[z*dstride + (long)(n0+n)*R + k0+kl] = tile[kl][n];
    }
}

__global__ void concat_bias_k(const void* bq, const void* bk, const void* bv, bf16* out,
                              const int* __restrict__ flagp){
    const int isf = *flagp;
    int i = blockIdx.x*256 + threadIdx.x;
    if (i >= NL_N*1536) return;
    int l = i/1536, n = i%1536;
    float v = (n<512) ? ldw(bq,l*512+n,isf) : (n<1024 ? ldw(bk,l*512+n-512,isf) : ldw(bv,l*512+n-1024,isf));
    out[i] = f2b(v);
}

// Vt[z][n][k]: n = head dim (64), k = key (576, zero pad k>=562); z = b*8+h over all 256
__global__ __launch_bounds__(256) void transpose_v_k(
    const bf16* __restrict__ qkv, bf16* __restrict__ Vt)
{
    __shared__ bf16 tl[64*33];
    int k0 = blockIdx.x * 32, z = blockIdx.z;
    int b = z >> 3, h = z & 7;
    int t = threadIdx.x;
    int n = t & 63, kb = t >> 6;
    #pragma unroll
    for (int i=0;i<8;i++) {
        int kl = kb + 4*i;
        int kg = k0 + kl;
        bf16 v = (kg < ST_N) ? qkv[((long)(b*ST_N + kg))*1536 + 1024 + h*64 + n] : f2b(0.f);
        tl[n*33 + kl] = v;
    }
    __syncthreads();
    int kk = t & 31, nb = t >> 5;
    #pragma unroll
    for (int i=0;i<8;i++) {
        int nn = nb + 8*i;
        Vt[((long)z*64 + nn)*STP_N + k0 + kk] = tl[nn*33 + kk];
    }
}

// ---------------- MFMA GEMM: C = A[M,K] @ Bt[N,K]^T ----------------
constexpr int EPI_BF16=0, EPI_F32=1, EPI_GELU=2, EPI_ATOMIC=3, EPI_BF16R=4;

template<int BM, int BN, int MODE>
__global__ __launch_bounds__(256,2) void gemm_k(
    const bf16* __restrict__ Ag, const bf16* __restrict__ Bg, void* __restrict__ Cg,
    const void* __restrict__ bias, long bias_off,
    int M, int N, int K, int lda, int ldb, int ldc, int Nst, int kch,
    const int* __restrict__ flagp)
{
    const int isf = *flagp;
    __shared__ bf16 lA[BM*32];
    __shared__ bf16 lB[BN*32];
    const int tid = threadIdx.x;
    const int tile_m = blockIdx.y * BM;
    const int tile_n = blockIdx.x * BN;

    bf16*  C16 = (bf16*)Cg;
    float* C32 = (float*)Cg;

    constexpr int WM = BM/2, WN = BN/2, MI = WM/16, NI = WN/16;
    const int w = tid>>6, lane = tid&63;
    const int wm = w>>1, wn = w&1;
    const int quad = lane>>4, lrow = lane&15;

    f32x4 zero = {0.f,0.f,0.f,0.f};
    f32x4 acc[MI][NI];
    #pragma unroll
    for (int i=0;i<MI;i++)
        #pragma unroll
        for (int j=0;j<NI;j++) acc[i][j] = zero;

    int ks = 0, ke = K;
    if (kch > 0) { ks = blockIdx.z * kch; ke = ks + kch; if (ke > K) ke = K; }

    for (int k0=ks;k0<ke;k0+=32) {
        __syncthreads();
        #pragma unroll
        for (int r=0;r<BM/64;r++) {
            int e = (r*256 + tid)*8;
            int row = e>>5, kk = e&31;
            int gr = tile_m + row; gr = gr < M ? gr : M-1;
            load_lds16(Ag + (long)gr*lda + k0 + kk, &lA[e]);
        }
        #pragma unroll
        for (int r=0;r<BN/64;r++) {
            int e = (r*256 + tid)*8;
            int row = e>>5, kk = e&31;
            int gr = tile_n + row; gr = gr < N ? gr : N-1;
            load_lds16(Bg + (long)gr*ldb + k0 + kk, &lB[e]);
        }
        __syncthreads();
        short8 afr[MI], bfr[NI];
        #pragma unroll
        for (int i=0;i<MI;i++) afr[i] = *(const short8*)&lA[(wm*WM + i*16 + lrow)*32 + quad*8];
        #pragma unroll
        for (int j=0;j<NI;j++) bfr[j] = *(const short8*)&lB[(wn*WN + j*16 + lrow)*32 + quad*8];
        #pragma unroll
        for (int i=0;i<MI;i++)
            #pragma unroll
            for (int j=0;j<NI;j++)
                acc[i][j] = __builtin_amdgcn_mfma_f32_16x16x32_bf16(afr[i], bfr[j], acc[i][j], 0, 0, 0);
    }

    #pragma unroll
    for (int i=0;i<MI;i++) {
        #pragma unroll
        for (int j=0;j<NI;j++) {
            int col = tile_n + wn*WN + j*16 + lrow;
            int rb  = tile_m + wm*WM + i*16 + quad*4;
            #pragma unroll
            for (int r=0;r<4;r++) {
                int row = rb + r;
                if (row >= M || col >= Nst) continue;
                float v = acc[i][j][r];
                if constexpr (MODE == EPI_BF16) {
                    C16[(long)row*ldc + col] = f2b(v + b2f(((const bf16*)bias)[bias_off + col]));
                } else if constexpr (MODE == EPI_F32) {
                    C32[(long)row*ldc + col] = v + ldw(bias, bias_off + col, isf);
                } else if constexpr (MODE == EPI_GELU) {
                    float x = v + ldw(bias, bias_off + col, isf);
                    C16[(long)row*ldc + col] = f2b(0.5f*x*(1.f + erff(x*0.70710678118654752f)));
                } else if constexpr (MODE == EPI_BF16R) {
                    C16[(long)row*ldc + col] = f2b(v + ldw(bias, bias_off + col, isf));
                } else { // EPI_ATOMIC
                    atomicAdd(&C32[(long)row*ldc + col], v);
                }
            }
        }
    }
}

// ---------------- flash attention ----------------
// grid: x = q-tile (0..4), z = b*8+h (0..255). 256 threads = 4 waves, wave owns 32 q rows.
// LDS rows are 64 bf16 with XOR-swizzled 8-elem chunks: chunk' = chunk ^ (row&7).
__global__ __launch_bounds__(256,2) void flash_k(
    const bf16* __restrict__ qkv, const bf16* __restrict__ Vt,
    bf16* __restrict__ ctx, const int* __restrict__ slens)
{
    __shared__ __align__(16) bf16 lQ[128*64];
    __shared__ __align__(16) bf16 lK[64*64];
    __shared__ __align__(16) bf16 lV[64*64];
    __shared__ __align__(16) bf16 lP[128*64];
    const int z = blockIdx.z, b = z>>3, h = z&7;
    const int qt = blockIdx.x;
    const int tid = threadIdx.x;
    const int w = tid>>6, lane = tid&63;
    const int quad = lane>>4, l15 = lane&15;
    int L = slens[b]; L = L<1?1:(L>S_N?S_N:L);
    const int lenT = L + T_N;

    #pragma unroll
    for (int rr=0;rr<4;rr++){
        int ci = rr*256 + tid;
        int row = ci>>3, c8 = (ci&7) ^ (row&7);
        int gr = qt*128 + row; gr = gr < ST_N ? gr : ST_N-1;
        load_lds16(qkv + ((long)(b*ST_N+gr))*1536 + h*64 + c8*8, &lQ[ci*8]);
    }

    f32x4 zerov = {0.f,0.f,0.f,0.f};
    f32x4 O[2][4];
    float m_i[2][4], l_i[2][4];
    #pragma unroll
    for (int i=0;i<2;i++){
        #pragma unroll
        for (int j=0;j<4;j++) O[i][j] = zerov;
        #pragma unroll
        for (int r=0;r<4;r++){ m_i[i][r]=-1e30f; l_i[i][r]=0.f; }
    }

    for (int kt=0; kt<9; kt++){
        __syncthreads();
        #pragma unroll
        for (int rr=0;rr<2;rr++){
            int ci = rr*256+tid;
            int row = ci>>3, c8 = (ci&7) ^ (row&7);
            int kr = kt*64+row; kr = kr < ST_N ? kr : ST_N-1;
            load_lds16(qkv + ((long)(b*ST_N+kr))*1536 + 512 + h*64 + c8*8, &lK[ci*8]);
        }
        #pragma unroll
        for (int rr=0;rr<2;rr++){
            int ci = rr*256+tid;
            int n = ci>>3, c8 = (ci&7) ^ (n&7);
            load_lds16(Vt + ((long)z*64+n)*STP_N + kt*64 + c8*8, &lV[ci*8]);
        }
        __syncthreads();

        f32x4 S[2][4];
        #pragma unroll
        for (int i=0;i<2;i++)
            #pragma unroll
            for (int j=0;j<4;j++) S[i][j] = zerov;
        #pragma unroll
        for (int kc=0;kc<2;kc++){
            short8 aQ[2], bK[4];
            #pragma unroll
            for (int i=0;i<2;i++){
                int row = w*32+i*16+l15;
                aQ[i] = *(const short8*)&lQ[row*64 + (((kc*4+quad) ^ (row&7))<<3)];
            }
            #pragma unroll
            for (int j=0;j<4;j++){
                int row = j*16+l15;
                bK[j] = *(const short8*)&lK[row*64 + (((kc*4+quad) ^ (row&7))<<3)];
            }
            #pragma unroll
            for (int i=0;i<2;i++)
                #pragma unroll
                for (int j=0;j<4;j++)
                    S[i][j] = __builtin_amdgcn_mfma_f32_16x16x32_bf16(aQ[i], bK[j], S[i][j], 0,0,0);
        }

        #pragma unroll
        for (int i=0;i<2;i++){
            #pragma unroll
            for (int r=0;r<4;r++){
                float mx = -1e30f;
                #pragma unroll
                for (int j=0;j<4;j++){
                    int col = kt*64 + j*16 + l15;
                    float s = S[i][j][r]*0.125f + (col < lenT ? 0.f : -10000.f);
                    S[i][j][r] = s;
                    mx = fmaxf(mx, s);
                }
                #pragma unroll
                for (int o=1;o<16;o<<=1) mx = fmaxf(mx, __shfl_xor(mx, o, 64));
                float mn = fmaxf(m_i[i][r], mx);
                float alpha = __expf(m_i[i][r] - mn);
                m_i[i][r] = mn;
                float sm = 0.f;
                #pragma unroll
                for (int j=0;j<4;j++){
                    float pv = __expf(S[i][j][r] - mn);
                    S[i][j][r] = pv;
                    sm += pv;
                }
                #pragma unroll
                for (int o=1;o<16;o<<=1) sm += __shfl_xor(sm, o, 64);
                l_i[i][r] = l_i[i][r]*alpha + sm;
                #pragma unroll
                for (int j=0;j<4;j++) O[i][j][r] *= alpha;
            }
        }

        #pragma unroll
        for (int i=0;i<2;i++)
            #pragma unroll
            for (int j=0;j<4;j++)
                #pragma unroll
                for (int r=0;r<4;r++){
                    int row = w*32 + i*16 + quad*4 + r;
                    int col = j*16 + l15;
                    lP[row*64 + (((col>>3) ^ (row&7))<<3) + (col&7)] = f2b(S[i][j][r]);
                }
        __syncthreads();

        #pragma unroll
        for (int kc=0;kc<2;kc++){
            short8 aP[2], bV[4];
            #pragma unroll
            for (int i=0;i<2;i++){
                int row = w*32+i*16+l15;
                aP[i] = *(const short8*)&lP[row*64 + (((kc*4+quad) ^ (row&7))<<3)];
            }
            #pragma unroll
            for (int j=0;j<4;j++){
                int row = j*16+l15;
                bV[j] = *(const short8*)&lV[row*64 + (((kc*4+quad) ^ (row&7))<<3)];
            }
            #pragma unroll
            for (int i=0;i<2;i++)
                #pragma unroll
                for (int j=0;j<4;j++)
                    O[i][j] = __builtin_amdgcn_mfma_f32_16x16x32_bf16(aP[i], bV[j], O[i][j], 0,0,0);
        }
    }

    #pragma unroll
    for (int i=0;i<2;i++)
        #pragma unroll
        for (int j=0;j<4;j++)
            #pragma unroll
            for (int r=0;r<4;r++){
                int row = qt*128 + w*32 + i*16 + quad*4 + r;
                if (row < ST_N)
                    ctx[((long)(b*ST_N+row))*512 + h*64 + j*16 + l15] = f2b(O[i][j][r] / l_i[i][r]);
            }
}

// ---------------- residual + LN (fp32 state + bf16 shadow), bf16 tmp ----------------
__global__ __launch_bounds__(256) void ln_residual_k(
    const bf16* __restrict__ tmp, float* __restrict__ hf, bf16* __restrict__ hb,
    const void* __restrict__ g, const void* __restrict__ bb, long goff,
    void* __restrict__ outp, int is_final, const int* __restrict__ flagp)
{
    const int isf = *flagp;
    const int of32 = is_final && isf;
    long base = (long)blockIdx.x * 512;
    int t = threadIdx.x;
    float v0 = hf[base+t]     + b2f(tmp[base+t]);
    float v1 = hf[base+t+256] + b2f(tmp[base+t+256]);
    __shared__ float red[4];
    float mean = block_reduce_sum(v0+v1, red, t) * (1.f/512.f);
    float d0=v0-mean, d1=v1-mean;
    __syncthreads();
    float var = block_reduce_sum(d0*d0+d1*d1, red, t) * (1.f/512.f);
    float rstd = rsqrtf(var + 1e-12f);
    float o0 = d0*rstd*ldw(g,goff+t,isf) + ldw(bb,goff+t,isf);
    float o1 = d1*rstd*ldw(g,goff+t+256,isf) + ldw(bb,goff+t+256,isf);
    hf[base+t]=o0; hf[base+t+256]=o1;
    hb[base+t]=f2b(o0); hb[base+t+256]=f2b(o1);
    if (of32) {
        ((float*)outp)[base+t]=o0; ((float*)outp)[base+t+256]=o1;
    } else {
        ((bf16*)outp)[base+t]=f2b(o0); ((bf16*)outp)[base+t+256]=f2b(o1);
    }
}

extern "C" void kernel_launch(void* const* d_in, const int* in_sizes, int n_in,
                              void* d_out, int out_size, void* d_ws, size_t ws_size,
                              hipStream_t stream)
{
    (void)in_sizes; (void)n_in; (void)out_size; (void)ws_size;
    const int*  ids   = (const int*) d_in[0];
    const int*  slens = (const int*) d_in[1];
    const void* embed = d_in[2];
    const void* Wdec  = d_in[3];
    const void* bdec  = d_in[4];
    const void* mW1   = d_in[5];
    const void* mb1   = d_in[6];
    const void* mW2   = d_in[7];
    const void* mb2   = d_in[8];
    const void* mlg   = d_in[9];
    const void* mlb   = d_in[10];
    const void* Wq    = d_in[11];
    const void* bq    = d_in[12];
    const void* Wk    = d_in[13];
    const void* bk    = d_in[14];
    const void* Wv    = d_in[15];
    const void* bv    = d_in[16];
    const void* Wo    = d_in[17];
    const void* bo    = d_in[18];
    const void* l1g   = d_in[19];
    const void* l1b   = d_in[20];
    const void* Wi    = d_in[21];
    const void* bi    = d_in[22];
    const void* Wf    = d_in[23];
    const void* bfv   = d_in[24];
    const void* l2g   = d_in[25];
    const void* l2b   = d_in[26];

    char* p = (char*)d_ws;
    auto alloc = [&](size_t bytes)->void* {
        void* r = (void*)p; p += (bytes + 255) & ~(size_t)255; return r; };
    int*   flag  = (int*)  alloc(256);
    float* pmax  = (float*)alloc((size_t)T_N*WCH_N*4);
    float* psum  = (float*)alloc((size_t)T_N*WCH_N*4);
    float* tmf   = (float*)alloc((size_t)T_N*512*4);
    bf16*  tmb   = (bf16*) alloc((size_t)T_N*512*2);
    float* hmem  = (float*)alloc((size_t)64*1024*4);
    bf16*  hrel  = (bf16*) alloc((size_t)64*1024*2);
    float* fcout = (float*)alloc((size_t)64*512*4);
    float* hidf  = (float*)alloc((size_t)NTOK_N*512*4);
    bf16*  hidb  = (bf16*) alloc((size_t)NTOK_N*512*2);
    bf16*  qkvt  = (bf16*) alloc((size_t)NL_N*1536*512*2);
    bf16*  wot   = (bf16*) alloc((size_t)NL_N*512*512*2);
    bf16*  wit   = (bf16*) alloc((size_t)NL_N*2048*512*2);
    bf16*  wft   = (bf16*) alloc((size_t)NL_N*512*2048*2);
    bf16*  bqkv  = (bf16*) alloc((size_t)NL_N*1536*2);
    // R1 union (time-disjoint): prelude [wdb 3.84M | W1t 61.5M | W2t 1M] <-> [qkv 55.25M] <-> [ffb 73.66M]
    char*  R1    = (char*) alloc((size_t)NTOK_N*2048*2);
    bf16*  wdb   = (bf16*)R1;
    bf16*  W1t   = (bf16*)(R1 + (size_t)64*VBP_N*2);
    bf16*  W2t   = (bf16*)(R1 + (size_t)64*VBP_N*2 + (size_t)1024*VBP_N*2);
    bf16*  qkv   = (bf16*)R1;
    bf16*  ffb   = (bf16*)R1;
    // RU2: ctx (18.42M) + [Vt 18.87M <-> tmp16 18.42M]
    bf16*  ctx   = (bf16*) alloc((size_t)NTOK_N*512*2);
    char*  RU2   = (char*) alloc((size_t)NTOK_N*512*4);
    bf16*  Vt    = (bf16*)RU2;
    bf16*  tmp16 = (bf16*)RU2;
    // total ~= 210 MB

    detect_k<<<1,256,0,stream>>>((const unsigned int*)embed, flag);

    // topic memory: parallel softmax -> FC1 (MFMA, K-split atomic) -> relu -> FC2 (MFMA) -> LN
    zero_u32_k<<<((64L*VBP_N/2)+255)/256,256,0,stream>>>((unsigned int*)wdb, 64L*VBP_N/2);
    zero_u32_k<<<((64L*1024)+255)/256,256,0,stream>>>((unsigned int*)hmem, 64L*1024);
    wd_partmax_k<<<dim3(WCH_N,T_N),256,0,stream>>>(Wdec,bdec,pmax,flag);
    wd_partsum_k<<<dim3(WCH_N,T_N),256,0,stream>>>(Wdec,bdec,pmax,psum,flag);
    wd_write_k  <<<dim3(WCH_N,T_N),256,0,stream>>>(Wdec,bdec,pmax,psum,wdb,flag);
    transpose_k<<<dim3(32,VBP_N/32,1),256,0,stream>>>(mW1, W1t, VBP_N, 1024, 0L, 0L, VB_N, flag);
    transpose_k<<<dim3(16,32,1),256,0,stream>>>(mW2, W2t, 1024, 512, 0L, 0L, 1024, flag);
    gemm_k<64,128,EPI_ATOMIC><<<dim3(8,1,32),256,0,stream>>>(
        wdb, W1t, hmem, nullptr, 0,
        64, 1024, VBP_N, VBP_N, VBP_N, 1024, 1024, 960, flag);
    relu_bias_k<<<64,256,0,stream>>>(hmem, mb1, hrel, flag);
    gemm_k<64,128,EPI_F32><<<dim3(4,1,1),256,0,stream>>>(
        hrel, W2t, fcout, mb2, 0,
        64, 512, 1024, 1024, 1024, 512, 512, 0, flag);
    ln_topic_k<<<T_N,256,0,stream>>>(fcout, mlg, mlb, tmf, tmb, flag);
    embed_insert_k<<<dim3(ST_N,B_N),256,0,stream>>>(ids, slens, embed, tmf, tmb, hidf, hidb, flag);

    // weight prep (canonical bf16, [N][K] layouts)
    transpose_k<<<dim3(16,16,NL_N),256,0,stream>>>(Wq, qkvt,          512, 512, 262144L, 786432L, 512, flag);
    transpose_k<<<dim3(16,16,NL_N),256,0,stream>>>(Wk, qkvt+262144,   512, 512, 262144L, 786432L, 512, flag);
    transpose_k<<<dim3(16,16,NL_N),256,0,stream>>>(Wv, qkvt+524288,   512, 512, 262144L, 786432L, 512, flag);
    transpose_k<<<dim3(16,16,NL_N),256,0,stream>>>(Wo, wot,           512, 512, 262144L, 262144L, 512, flag);
    transpose_k<<<dim3(64,16,NL_N),256,0,stream>>>(Wi, wit,           512, 2048, 1048576L, 1048576L, 512, flag);
    transpose_k<<<dim3(16,64,NL_N),256,0,stream>>>(Wf, wft,           2048, 512, 1048576L, 1048576L, 2048, flag);
    concat_bias_k<<<(NL_N*1536+255)/256,256,0,stream>>>(bq,bk,bv,bqkv,flag);

    for (int l=0;l<NL_N;l++) {
        gemm_k<128,128,EPI_BF16><<<dim3(12,141,1),256,0,stream>>>(
            hidb, qkvt + (size_t)l*786432, qkv, bqkv, (long)l*1536,
            NTOK_N, 1536, 512, 512, 512, 1536, 1536, 0, flag);
        transpose_v_k<<<dim3(18,1,256),256,0,stream>>>(qkv, Vt);
        flash_k<<<dim3(5,1,256),256,0,stream>>>(qkv, Vt, ctx, slens);
        gemm_k<128,128,EPI_BF16R><<<dim3(4,141,1),256,0,stream>>>(
            ctx, wot + (size_t)l*262144, tmp16, bo, (long)l*512,
            NTOK_N, 512, 512, 512, 512, 512, 512, 0, flag);
        ln_residual_k<<<NTOK_N,256,0,stream>>>(tmp16, hidf, hidb, l1g, l1b, (long)l*512,
                                               hidb, 0, flag);
        gemm_k<128,128,EPI_GELU><<<dim3(16,141,1),256,0,stream>>>(
            hidb, wit + (size_t)l*1048576, ffb, bi, (long)l*2048,
            NTOK_N, 2048, 512, 512, 512, 2048, 2048, 0, flag);
        gemm_k<128,128,EPI_BF16R><<<dim3(4,141,1),256,0,stream>>>(
            ffb, wft + (size_t)l*1048576, tmp16, bfv, (long)l*512,
            NTOK_N, 512, 2048, 2048, 2048, 512, 512, 0, flag);
        ln_residual_k<<<NTOK_N,256,0,stream>>>(tmp16, hidf, hidb, l2g, l2b, (long)l*512,
                                               (l == NL_N-1) ? d_out : (void*)hidb,
                                               (l == NL_N-1) ? 1 : 0, flag);
    }
}

// Round 6
// 1859.991 us; speedup vs baseline: 2.1209x; 1.0630x over previous
//
#include <hip/hip_runtime.h>
#include <hip/hip_bf16.h>
#include <math.h>

using bf16 = __hip_bfloat16;
typedef __attribute__((ext_vector_type(4))) float f32x4;
typedef __attribute__((ext_vector_type(8))) short short8;

#define B_N 32
#define S_N 512
#define T_N 50
#define H_N 8
#define NL_N 4
#define VB_N 30000
#define VBP_N 30016          // VB padded to mult of 64
#define ST_N 562
#define STP_N 576
#define NTOK_N (B_N*ST_N)   // 17984
#define WCH_N 16             // softmax_wdec column chunks
#define WCW_N 1875           // 30000/16

__device__ __forceinline__ float b2f(bf16 x){ return __bfloat162float(x); }
__device__ __forceinline__ bf16  f2b(float x){ return __float2bfloat16(x); }
// flag-aware raw-input load: f==1 -> buffer is float32, else bf16
__device__ __forceinline__ float ldw(const void* p, long i, int f){
    return f ? ((const float*)p)[i] : __bfloat162float(((const bf16*)p)[i]);
}

__device__ __forceinline__ void load_lds16(const void* g, void* l){
    __builtin_amdgcn_global_load_lds((const __attribute__((address_space(1))) void*)g,
                                     (__attribute__((address_space(3))) void*)l, 16, 0, 0);
}

__device__ __forceinline__ float block_reduce_max(float v, float* red, int t){
    for (int o=32;o>0;o>>=1) v = fmaxf(v, __shfl_down(v,o,64));
    int w=t>>6, lane=t&63;
    if (lane==0) red[w]=v;
    __syncthreads();
    return fmaxf(fmaxf(red[0],red[1]),fmaxf(red[2],red[3]));
}
__device__ __forceinline__ float block_reduce_sum(float v, float* red, int t){
    for (int o=32;o>0;o>>=1) v += __shfl_down(v,o,64);
    int w=t>>6, lane=t&63;
    if (lane==0) red[w]=v;
    __syncthreads();
    return red[0]+red[1]+red[2]+red[3];
}

// ---------------- dtype detector ----------------
__global__ __launch_bounds__(256) void detect_k(const unsigned int* __restrict__ w, int* flag)
{
    int t = threadIdx.x;
    float s = 0.f;
    for (int i=t;i<4096;i+=256){ int e = (w[i]>>7)&0xFF; s += fabsf((float)e - 120.f); }
    __shared__ float red[4];
    for (int o=32;o>0;o>>=1) s += __shfl_down(s,o,64);
    int wv=t>>6, lane=t&63;
    if (lane==0) red[wv]=s;
    __syncthreads();
    if (t==0) flag[0] = ((red[0]+red[1]+red[2]+red[3]) * (1.f/4096.f) > 20.f) ? 1 : 0;
}

__global__ void zero_u32_k(unsigned int* p, long n){
    long i = (long)blockIdx.x*256 + threadIdx.x;
    if (i < n) p[i] = 0u;
}

// ---------------- topic memory: parallel W_dec softmax ----------------
__global__ __launch_bounds__(256) void wd_partmax_k(
    const void* __restrict__ Wd, const void* __restrict__ bd,
    float* __restrict__ pmax, const int* __restrict__ flagp)
{
    const int isf = *flagp;
    int ch = blockIdx.x, r = blockIdx.y, t = threadIdx.x;
    int c0 = ch*WCW_N, c1 = c0 + WCW_N;
    __shared__ float red[4];
    float mx = -1e30f;
    for (int c=c0+t;c<c1;c+=256) mx = fmaxf(mx, ldw(Wd,(long)r*VB_N+c,isf) + ldw(bd,c,isf));
    mx = block_reduce_max(mx, red, t);
    if (t==0) pmax[r*WCH_N + ch] = mx;
}

__global__ __launch_bounds__(256) void wd_partsum_k(
    const void* __restrict__ Wd, const void* __restrict__ bd,
    const float* __restrict__ pmax, float* __restrict__ psum, const int* __restrict__ flagp)
{
    const int isf = *flagp;
    int ch = blockIdx.x, r = blockIdx.y, t = threadIdx.x;
    float mx = -1e30f;
    #pragma unroll
    for (int i=0;i<WCH_N;i++) mx = fmaxf(mx, pmax[r*WCH_N+i]);
    int c0 = ch*WCW_N, c1 = c0 + WCW_N;
    __shared__ float red[4];
    float sm = 0.f;
    for (int c=c0+t;c<c1;c+=256) sm += __expf(ldw(Wd,(long)r*VB_N+c,isf) + ldw(bd,c,isf) - mx);
    sm = block_reduce_sum(sm, red, t);
    if (t==0) psum[r*WCH_N + ch] = sm;
}

__global__ __launch_bounds__(256) void wd_write_k(
    const void* __restrict__ Wd, const void* __restrict__ bd,
    const float* __restrict__ pmax, const float* __restrict__ psum,
    bf16* __restrict__ wdb, const int* __restrict__ flagp)
{
    const int isf = *flagp;
    int ch = blockIdx.x, r = blockIdx.y, t = threadIdx.x;
    float mx = -1e30f, sm = 0.f;
    #pragma unroll
    for (int i=0;i<WCH_N;i++){ mx = fmaxf(mx, pmax[r*WCH_N+i]); sm += psum[r*WCH_N+i]; }
    float inv = 1.f/sm;
    int c0 = ch*WCW_N, c1 = c0 + WCW_N;
    for (int c=c0+t;c<c1;c+=256)
        wdb[(long)r*VBP_N + c] = f2b(__expf(ldw(Wd,(long)r*VB_N+c,isf) + ldw(bd,c,isf) - mx)*inv);
}

// hrel[64][1024] bf16 = relu(hmem + b1), rows >= T_N zeroed
__global__ __launch_bounds__(256) void relu_bias_k(
    const float* __restrict__ hmem, const void* __restrict__ b1,
    bf16* __restrict__ hrel, const int* __restrict__ flagp)
{
    const int isf = *flagp;
    int r = blockIdx.x, t = threadIdx.x;
    for (int c=t;c<1024;c+=256){
        float v = (r < T_N) ? fmaxf(hmem[r*1024+c] + ldw(b1,c,isf), 0.f) : 0.f;
        hrel[r*1024+c] = f2b(v);
    }
}

// plain LN over 50 rows of fcout[64][512] (bias b2 already added in GEMM epilogue)
__global__ __launch_bounds__(256) void ln_topic_k(
    const float* __restrict__ fcout,
    const void* __restrict__ lg, const void* __restrict__ lb,
    float* __restrict__ tmf, bf16* __restrict__ tmb, const int* __restrict__ flagp)
{
    const int isf = *flagp;
    int r = blockIdx.x, t = threadIdx.x;
    float a0 = fcout[r*512+t], a1 = fcout[r*512+t+256];
    __shared__ float red[4];
    float mean = block_reduce_sum(a0+a1, red, t) * (1.f/512.f);
    float d0=a0-mean, d1=a1-mean;
    __syncthreads();
    float var = block_reduce_sum(d0*d0+d1*d1, red, t) * (1.f/512.f);
    float rstd = rsqrtf(var + 1e-12f);
    float o0 = d0*rstd*ldw(lg,t,isf) + ldw(lb,t,isf);
    float o1 = d1*rstd*ldw(lg,t+256,isf) + ldw(lb,t+256,isf);
    tmf[r*512+t]=o0; tmf[r*512+t+256]=o1;
    tmb[r*512+t]=f2b(o0); tmb[r*512+t+256]=f2b(o1);
}

// ---------------- embedding + ragged insert ----------------
__global__ __launch_bounds__(256) void embed_insert_k(
    const int* __restrict__ ids, const int* __restrict__ lens,
    const void* __restrict__ embed, const float* __restrict__ tmf,
    const bf16* __restrict__ tmb, float* __restrict__ hf, bf16* __restrict__ hb,
    const int* __restrict__ flagp)
{
    const int isf = *flagp;
    int j = blockIdx.x, b = blockIdx.y, t = threadIdx.x;
    int L = lens[b]; L = L<1?1:(L>S_N?S_N:L);
    long orow = ((long)b*ST_N + j)*512;
    if (j >= L && j < L + T_N) {
        int m = j - L;
        for (int c=t;c<512;c+=256){ float v = tmf[m*512+c]; hf[orow+c]=v; hb[orow+c]=tmb[m*512+c]; }
    } else {
        int sj = (j < L) ? j : j - T_N;   // in [0, 511]
        int id = ids[b*S_N + sj];
        for (int c=t;c<512;c+=256){ float e = ldw(embed,(long)id*512+c,isf); hf[orow+c]=e; hb[orow+c]=f2b(e); }
    }
}

// ---------------- weight prep ----------------
// dst[z*dstride + (n0+n)*R + (k0+k)] = src[z*sstride + min(k0+k,Ksrc-1)*C + (n0+n)]
__global__ __launch_bounds__(256) void transpose_k(
    const void* __restrict__ src, bf16* __restrict__ dst,
    int R, int C, long sstride, long dstride, int Ksrc, const int* __restrict__ flagp)
{
    const int isf = *flagp;
    __shared__ bf16 tile[32][33];
    int n0 = blockIdx.x * 32, k0 = blockIdx.y * 32, z = blockIdx.z;
    int t = threadIdx.x;
    int nl = t & 31, kb = t >> 5;
    #pragma unroll
    for (int i=0;i<4;i++) {
        int k = k0 + kb + i*8; k = k < Ksrc ? k : Ksrc-1;
        tile[kb+i*8][nl] = f2b(ldw(src, z*sstride + (long)k*C + n0+nl, isf));
    }
    __syncthreads();
    int kl = t & 31, nb = t >> 5;
    #pragma unroll
    for (int i=0;i<4;i++) {
        int n = nb + i*8;
        dst[z*dstride + (long)(n0+n)*R + k0+kl] = tile[kl][n];
    }
}

__global__ void concat_bias_k(const void* bq, const void* bk, const void* bv, bf16* out,
                              const int* __restrict__ flagp){
    const int isf = *flagp;
    int i = blockIdx.x*256 + threadIdx.x;
    if (i >= NL_N*1536) return;
    int l = i/1536, n = i%1536;
    float v = (n<512) ? ldw(bq,l*512+n,isf) : (n<1024 ? ldw(bk,l*512+n-512,isf) : ldw(bv,l*512+n-1024,isf));
    out[i] = f2b(v);
}

// Vt[z][n][k]: n = head dim (64), k = key (576, zero pad k>=562); z = b*8+h over all 256
__global__ __launch_bounds__(256) void transpose_v_k(
    const bf16* __restrict__ qkv, bf16* __restrict__ Vt)
{
    __shared__ bf16 tl[64*33];
    int k0 = blockIdx.x * 32, z = blockIdx.z;
    int b = z >> 3, h = z & 7;
    int t = threadIdx.x;
    int n = t & 63, kb = t >> 6;
    #pragma unroll
    for (int i=0;i<8;i++) {
        int kl = kb + 4*i;
        int kg = k0 + kl;
        bf16 v = (kg < ST_N) ? qkv[((long)(b*ST_N + kg))*1536 + 1024 + h*64 + n] : f2b(0.f);
        tl[n*33 + kl] = v;
    }
    __syncthreads();
    int kk = t & 31, nb = t >> 5;
    #pragma unroll
    for (int i=0;i<8;i++) {
        int nn = nb + 8*i;
        Vt[((long)z*64 + nn)*STP_N + k0 + kk] = tl[nn*33 + kk];
    }
}

// ---------------- MFMA GEMM: C = A[M,K] @ Bt[N,K]^T ----------------
// BK=64 (128 B rows, full 32-bank span) with XOR-8 chunk swizzle:
// LDS chunk p of row r holds global chunk p^(r&7); per 16-lane phase the 8
// chunk positions are hit exactly 2x -> 2-way (free, m136). K must be mult of 64.
constexpr int EPI_BF16=0, EPI_F32=1, EPI_GELU=2, EPI_ATOMIC=3, EPI_BF16R=4;

template<int BM, int BN, int MODE>
__global__ __launch_bounds__(256,4) void gemm_k(
    const bf16* __restrict__ Ag, const bf16* __restrict__ Bg, void* __restrict__ Cg,
    const void* __restrict__ bias, long bias_off,
    int M, int N, int K, int lda, int ldb, int ldc, int Nst, int kch,
    const int* __restrict__ flagp)
{
    const int isf = *flagp;
    __shared__ __align__(16) bf16 lA[BM*64];
    __shared__ __align__(16) bf16 lB[BN*64];
    const int tid = threadIdx.x;
    const int tile_m = blockIdx.y * BM;
    const int tile_n = blockIdx.x * BN;

    bf16*  C16 = (bf16*)Cg;
    float* C32 = (float*)Cg;

    constexpr int WM = BM/2, WN = BN/2, MI = WM/16, NI = WN/16;
    const int w = tid>>6, lane = tid&63;
    const int wm = w>>1, wn = w&1;
    const int quad = lane>>4, lrow = lane&15;

    f32x4 zero = {0.f,0.f,0.f,0.f};
    f32x4 acc[MI][NI];
    #pragma unroll
    for (int i=0;i<MI;i++)
        #pragma unroll
        for (int j=0;j<NI;j++) acc[i][j] = zero;

    int ks = 0, ke = K;
    if (kch > 0) { ks = blockIdx.z * kch; ke = ks + kch; if (ke > K) ke = K; }

    for (int k0=ks;k0<ke;k0+=64) {
        __syncthreads();
        #pragma unroll
        for (int r=0;r<BM/32;r++) {
            int e = r*256 + tid;             // [0, BM*8)
            int row = e>>3, c8 = (e&7) ^ (row&7);
            int gr = tile_m + row; gr = gr < M ? gr : M-1;
            load_lds16(Ag + (long)gr*lda + k0 + c8*8, &lA[e*8]);
        }
        #pragma unroll
        for (int r=0;r<BN/32;r++) {
            int e = r*256 + tid;
            int row = e>>3, c8 = (e&7) ^ (row&7);
            int gr = tile_n + row; gr = gr < N ? gr : N-1;
            load_lds16(Bg + (long)gr*ldb + k0 + c8*8, &lB[e*8]);
        }
        __syncthreads();
        #pragma unroll
        for (int kc=0;kc<2;kc++){
            short8 afr[MI], bfr[NI];
            #pragma unroll
            for (int i=0;i<MI;i++){
                int row = wm*WM + i*16 + lrow;
                afr[i] = *(const short8*)&lA[row*64 + (((kc*4+quad) ^ (row&7))<<3)];
            }
            #pragma unroll
            for (int j=0;j<NI;j++){
                int row = wn*WN + j*16 + lrow;
                bfr[j] = *(const short8*)&lB[row*64 + (((kc*4+quad) ^ (row&7))<<3)];
            }
            #pragma unroll
            for (int i=0;i<MI;i++)
                #pragma unroll
                for (int j=0;j<NI;j++)
                    acc[i][j] = __builtin_amdgcn_mfma_f32_16x16x32_bf16(afr[i], bfr[j], acc[i][j], 0, 0, 0);
        }
    }

    #pragma unroll
    for (int i=0;i<MI;i++) {
        #pragma unroll
        for (int j=0;j<NI;j++) {
            int col = tile_n + wn*WN + j*16 + lrow;
            int rb  = tile_m + wm*WM + i*16 + quad*4;
            #pragma unroll
            for (int r=0;r<4;r++) {
                int row = rb + r;
                if (row >= M || col >= Nst) continue;
                float v = acc[i][j][r];
                if constexpr (MODE == EPI_BF16) {
                    C16[(long)row*ldc + col] = f2b(v + b2f(((const bf16*)bias)[bias_off + col]));
                } else if constexpr (MODE == EPI_F32) {
                    C32[(long)row*ldc + col] = v + ldw(bias, bias_off + col, isf);
                } else if constexpr (MODE == EPI_GELU) {
                    float x = v + ldw(bias, bias_off + col, isf);
                    C16[(long)row*ldc + col] = f2b(0.5f*x*(1.f + erff(x*0.70710678118654752f)));
                } else if constexpr (MODE == EPI_BF16R) {
                    C16[(long)row*ldc + col] = f2b(v + ldw(bias, bias_off + col, isf));
                } else { // EPI_ATOMIC
                    atomicAdd(&C32[(long)row*ldc + col], v);
                }
            }
        }
    }
}

// ---------------- flash attention ----------------
__global__ __launch_bounds__(256,2) void flash_k(
    const bf16* __restrict__ qkv, const bf16* __restrict__ Vt,
    bf16* __restrict__ ctx, const int* __restrict__ slens)
{
    __shared__ __align__(16) bf16 lQ[128*64];
    __shared__ __align__(16) bf16 lK[64*64];
    __shared__ __align__(16) bf16 lV[64*64];
    __shared__ __align__(16) bf16 lP[128*64];
    const int z = blockIdx.z, b = z>>3, h = z&7;
    const int qt = blockIdx.x;
    const int tid = threadIdx.x;
    const int w = tid>>6, lane = tid&63;
    const int quad = lane>>4, l15 = lane&15;
    int L = slens[b]; L = L<1?1:(L>S_N?S_N:L);
    const int lenT = L + T_N;

    #pragma unroll
    for (int rr=0;rr<4;rr++){
        int ci = rr*256 + tid;
        int row = ci>>3, c8 = (ci&7) ^ (row&7);
        int gr = qt*128 + row; gr = gr < ST_N ? gr : ST_N-1;
        load_lds16(qkv + ((long)(b*ST_N+gr))*1536 + h*64 + c8*8, &lQ[ci*8]);
    }

    f32x4 zerov = {0.f,0.f,0.f,0.f};
    f32x4 O[2][4];
    float m_i[2][4], l_i[2][4];
    #pragma unroll
    for (int i=0;i<2;i++){
        #pragma unroll
        for (int j=0;j<4;j++) O[i][j] = zerov;
        #pragma unroll
        for (int r=0;r<4;r++){ m_i[i][r]=-1e30f; l_i[i][r]=0.f; }
    }

    for (int kt=0; kt<9; kt++){
        __syncthreads();
        #pragma unroll
        for (int rr=0;rr<2;rr++){
            int ci = rr*256+tid;
            int row = ci>>3, c8 = (ci&7) ^ (row&7);
            int kr = kt*64+row; kr = kr < ST_N ? kr : ST_N-1;
            load_lds16(qkv + ((long)(b*ST_N+kr))*1536 + 512 + h*64 + c8*8, &lK[ci*8]);
        }
        #pragma unroll
        for (int rr=0;rr<2;rr++){
            int ci = rr*256+tid;
            int n = ci>>3, c8 = (ci&7) ^ (n&7);
            load_lds16(Vt + ((long)z*64+n)*STP_N + kt*64 + c8*8, &lV[ci*8]);
        }
        __syncthreads();

        f32x4 S[2][4];
        #pragma unroll
        for (int i=0;i<2;i++)
            #pragma unroll
            for (int j=0;j<4;j++) S[i][j] = zerov;
        #pragma unroll
        for (int kc=0;kc<2;kc++){
            short8 aQ[2], bK[4];
            #pragma unroll
            for (int i=0;i<2;i++){
                int row = w*32+i*16+l15;
                aQ[i] = *(const short8*)&lQ[row*64 + (((kc*4+quad) ^ (row&7))<<3)];
            }
            #pragma unroll
            for (int j=0;j<4;j++){
                int row = j*16+l15;
                bK[j] = *(const short8*)&lK[row*64 + (((kc*4+quad) ^ (row&7))<<3)];
            }
            #pragma unroll
            for (int i=0;i<2;i++)
                #pragma unroll
                for (int j=0;j<4;j++)
                    S[i][j] = __builtin_amdgcn_mfma_f32_16x16x32_bf16(aQ[i], bK[j], S[i][j], 0,0,0);
        }

        #pragma unroll
        for (int i=0;i<2;i++){
            #pragma unroll
            for (int r=0;r<4;r++){
                float mx = -1e30f;
                #pragma unroll
                for (int j=0;j<4;j++){
                    int col = kt*64 + j*16 + l15;
                    float s = S[i][j][r]*0.125f + (col < lenT ? 0.f : -10000.f);
                    S[i][j][r] = s;
                    mx = fmaxf(mx, s);
                }
                #pragma unroll
                for (int o=1;o<16;o<<=1) mx = fmaxf(mx, __shfl_xor(mx, o, 64));
                float mn = fmaxf(m_i[i][r], mx);
                float alpha = __expf(m_i[i][r] - mn);
                m_i[i][r] = mn;
                float sm = 0.f;
                #pragma unroll
                for (int j=0;j<4;j++){
                    float pv = __expf(S[i][j][r] - mn);
                    S[i][j][r] = pv;
                    sm += pv;
                }
                #pragma unroll
                for (int o=1;o<16;o<<=1) sm += __shfl_xor(sm, o, 64);
                l_i[i][r] = l_i[i][r]*alpha + sm;
                #pragma unroll
                for (int j=0;j<4;j++) O[i][j][r] *= alpha;
            }
        }

        #pragma unroll
        for (int i=0;i<2;i++)
            #pragma unroll
            for (int j=0;j<4;j++)
                #pragma unroll
                for (int r=0;r<4;r++){
                    int row = w*32 + i*16 + quad*4 + r;
                    int col = j*16 + l15;
                    lP[row*64 + (((col>>3) ^ (row&7))<<3) + (col&7)] = f2b(S[i][j][r]);
                }
        __syncthreads();

        #pragma unroll
        for (int kc=0;kc<2;kc++){
            short8 aP[2], bV[4];
            #pragma unroll
            for (int i=0;i<2;i++){
                int row = w*32+i*16+l15;
                aP[i] = *(const short8*)&lP[row*64 + (((kc*4+quad) ^ (row&7))<<3)];
            }
            #pragma unroll
            for (int j=0;j<4;j++){
                int row = j*16+l15;
                bV[j] = *(const short8*)&lV[row*64 + (((kc*4+quad) ^ (row&7))<<3)];
            }
            #pragma unroll
            for (int i=0;i<2;i++)
                #pragma unroll
                for (int j=0;j<4;j++)
                    O[i][j] = __builtin_amdgcn_mfma_f32_16x16x32_bf16(aP[i], bV[j], O[i][j], 0,0,0);
        }
    }

    #pragma unroll
    for (int i=0;i<2;i++)
        #pragma unroll
        for (int j=0;j<4;j++)
            #pragma unroll
            for (int r=0;r<4;r++){
                int row = qt*128 + w*32 + i*16 + quad*4 + r;
                if (row < ST_N)
                    ctx[((long)(b*ST_N+row))*512 + h*64 + j*16 + l15] = f2b(O[i][j][r] / l_i[i][r]);
            }
}

// ---------------- residual + LN (fp32 state + bf16 shadow), bf16 tmp ----------------
__global__ __launch_bounds__(256) void ln_residual_k(
    const bf16* __restrict__ tmp, float* __restrict__ hf, bf16* __restrict__ hb,
    const void* __restrict__ g, const void* __restrict__ bb, long goff,
    void* __restrict__ outp, int is_final, const int* __restrict__ flagp)
{
    const int isf = *flagp;
    const int of32 = is_final && isf;
    long base = (long)blockIdx.x * 512;
    int t = threadIdx.x;
    float v0 = hf[base+t]     + b2f(tmp[base+t]);
    float v1 = hf[base+t+256] + b2f(tmp[base+t+256]);
    __shared__ float red[4];
    float mean = block_reduce_sum(v0+v1, red, t) * (1.f/512.f);
    float d0=v0-mean, d1=v1-mean;
    __syncthreads();
    float var = block_reduce_sum(d0*d0+d1*d1, red, t) * (1.f/512.f);
    float rstd = rsqrtf(var + 1e-12f);
    float o0 = d0*rstd*ldw(g,goff+t,isf) + ldw(bb,goff+t,isf);
    float o1 = d1*rstd*ldw(g,goff+t+256,isf) + ldw(bb,goff+t+256,isf);
    hf[base+t]=o0; hf[base+t+256]=o1;
    hb[base+t]=f2b(o0); hb[base+t+256]=f2b(o1);
    if (of32) {
        ((float*)outp)[base+t]=o0; ((float*)outp)[base+t+256]=o1;
    } else {
        ((bf16*)outp)[base+t]=f2b(o0); ((bf16*)outp)[base+t+256]=f2b(o1);
    }
}

extern "C" void kernel_launch(void* const* d_in, const int* in_sizes, int n_in,
                              void* d_out, int out_size, void* d_ws, size_t ws_size,
                              hipStream_t stream)
{
    (void)in_sizes; (void)n_in; (void)out_size; (void)ws_size;
    const int*  ids   = (const int*) d_in[0];
    const int*  slens = (const int*) d_in[1];
    const void* embed = d_in[2];
    const void* Wdec  = d_in[3];
    const void* bdec  = d_in[4];
    const void* mW1   = d_in[5];
    const void* mb1   = d_in[6];
    const void* mW2   = d_in[7];
    const void* mb2   = d_in[8];
    const void* mlg   = d_in[9];
    const void* mlb   = d_in[10];
    const void* Wq    = d_in[11];
    const void* bq    = d_in[12];
    const void* Wk    = d_in[13];
    const void* bk    = d_in[14];
    const void* Wv    = d_in[15];
    const void* bv    = d_in[16];
    const void* Wo    = d_in[17];
    const void* bo    = d_in[18];
    const void* l1g   = d_in[19];
    const void* l1b   = d_in[20];
    const void* Wi    = d_in[21];
    const void* bi    = d_in[22];
    const void* Wf    = d_in[23];
    const void* bfv   = d_in[24];
    const void* l2g   = d_in[25];
    const void* l2b   = d_in[26];

    char* p = (char*)d_ws;
    auto alloc = [&](size_t bytes)->void* {
        void* r = (void*)p; p += (bytes + 255) & ~(size_t)255; return r; };
    int*   flag  = (int*)  alloc(256);
    float* pmax  = (float*)alloc((size_t)T_N*WCH_N*4);
    float* psum  = (float*)alloc((size_t)T_N*WCH_N*4);
    float* tmf   = (float*)alloc((size_t)T_N*512*4);
    bf16*  tmb   = (bf16*) alloc((size_t)T_N*512*2);
    float* hmem  = (float*)alloc((size_t)64*1024*4);
    bf16*  hrel  = (bf16*) alloc((size_t)64*1024*2);
    float* fcout = (float*)alloc((size_t)64*512*4);
    float* hidf  = (float*)alloc((size_t)NTOK_N*512*4);
    bf16*  hidb  = (bf16*) alloc((size_t)NTOK_N*512*2);
    bf16*  qkvt  = (bf16*) alloc((size_t)NL_N*1536*512*2);
    bf16*  wot   = (bf16*) alloc((size_t)NL_N*512*512*2);
    bf16*  wit   = (bf16*) alloc((size_t)NL_N*2048*512*2);
    bf16*  wft   = (bf16*) alloc((size_t)NL_N*512*2048*2);
    bf16*  bqkv  = (bf16*) alloc((size_t)NL_N*1536*2);
    // R1 union (time-disjoint): prelude [wdb 3.84M | W1t 61.5M | W2t 1M] <-> [qkv 55.25M] <-> [ffb 73.66M]
    char*  R1    = (char*) alloc((size_t)NTOK_N*2048*2);
    bf16*  wdb   = (bf16*)R1;
    bf16*  W1t   = (bf16*)(R1 + (size_t)64*VBP_N*2);
    bf16*  W2t   = (bf16*)(R1 + (size_t)64*VBP_N*2 + (size_t)1024*VBP_N*2);
    bf16*  qkv   = (bf16*)R1;
    bf16*  ffb   = (bf16*)R1;
    // RU2: ctx (18.42M) + [Vt 18.87M <-> tmp16 18.42M]
    bf16*  ctx   = (bf16*) alloc((size_t)NTOK_N*512*2);
    char*  RU2   = (char*) alloc((size_t)NTOK_N*512*4);
    bf16*  Vt    = (bf16*)RU2;
    bf16*  tmp16 = (bf16*)RU2;
    // total ~= 210 MB

    detect_k<<<1,256,0,stream>>>((const unsigned int*)embed, flag);

    // topic memory: parallel softmax -> FC1 (MFMA, K-split atomic) -> relu -> FC2 (MFMA) -> LN
    zero_u32_k<<<((64L*VBP_N/2)+255)/256,256,0,stream>>>((unsigned int*)wdb, 64L*VBP_N/2);
    zero_u32_k<<<((64L*1024)+255)/256,256,0,stream>>>((unsigned int*)hmem, 64L*1024);
    wd_partmax_k<<<dim3(WCH_N,T_N),256,0,stream>>>(Wdec,bdec,pmax,flag);
    wd_partsum_k<<<dim3(WCH_N,T_N),256,0,stream>>>(Wdec,bdec,pmax,psum,flag);
    wd_write_k  <<<dim3(WCH_N,T_N),256,0,stream>>>(Wdec,bdec,pmax,psum,wdb,flag);
    transpose_k<<<dim3(32,VBP_N/32,1),256,0,stream>>>(mW1, W1t, VBP_N, 1024, 0L, 0L, VB_N, flag);
    transpose_k<<<dim3(16,32,1),256,0,stream>>>(mW2, W2t, 1024, 512, 0L, 0L, 1024, flag);
    gemm_k<64,128,EPI_ATOMIC><<<dim3(8,1,32),256,0,stream>>>(
        wdb, W1t, hmem, nullptr, 0,
        64, 1024, VBP_N, VBP_N, VBP_N, 1024, 1024, 960, flag);
    relu_bias_k<<<64,256,0,stream>>>(hmem, mb1, hrel, flag);
    gemm_k<64,128,EPI_F32><<<dim3(4,1,1),256,0,stream>>>(
        hrel, W2t, fcout, mb2, 0,
        64, 512, 1024, 1024, 1024, 512, 512, 0, flag);
    ln_topic_k<<<T_N,256,0,stream>>>(fcout, mlg, mlb, tmf, tmb, flag);
    embed_insert_k<<<dim3(ST_N,B_N),256,0,stream>>>(ids, slens, embed, tmf, tmb, hidf, hidb, flag);

    // weight prep (canonical bf16, [N][K] layouts)
    transpose_k<<<dim3(16,16,NL_N),256,0,stream>>>(Wq, qkvt,          512, 512, 262144L, 786432L, 512, flag);
    transpose_k<<<dim3(16,16,NL_N),256,0,stream>>>(Wk, qkvt+262144,   512, 512, 262144L, 786432L, 512, flag);
    transpose_k<<<dim3(16,16,NL_N),256,0,stream>>>(Wv, qkvt+524288,   512, 512, 262144L, 786432L, 512, flag);
    transpose_k<<<dim3(16,16,NL_N),256,0,stream>>>(Wo, wot,           512, 512, 262144L, 262144L, 512, flag);
    transpose_k<<<dim3(64,16,NL_N),256,0,stream>>>(Wi, wit,           512, 2048, 1048576L, 1048576L, 512, flag);
    transpose_k<<<dim3(16,64,NL_N),256,0,stream>>>(Wf, wft,           2048, 512, 1048576L, 1048576L, 2048, flag);
    concat_bias_k<<<(NL_N*1536+255)/256,256,0,stream>>>(bq,bk,bv,bqkv,flag);

    for (int l=0;l<NL_N;l++) {
        gemm_k<128,128,EPI_BF16><<<dim3(12,141,1),256,0,stream>>>(
            hidb, qkvt + (size_t)l*786432, qkv, bqkv, (long)l*1536,
            NTOK_N, 1536, 512, 512, 512, 1536, 1536, 0, flag);
        transpose_v_k<<<dim3(18,1,256),256,0,stream>>>(qkv, Vt);
        flash_k<<<dim3(5,1,256),256,0,stream>>>(qkv, Vt, ctx, slens);
        gemm_k<128,128,EPI_BF16R><<<dim3(4,141,1),256,0,stream>>>(
            ctx, wot + (size_t)l*262144, tmp16, bo, (long)l*512,
            NTOK_N, 512, 512, 512, 512, 512, 512, 0, flag);
        ln_residual_k<<<NTOK_N,256,0,stream>>>(tmp16, hidf, hidb, l1g, l1b, (long)l*512,
                                               hidb, 0, flag);
        gemm_k<128,128,EPI_GELU><<<dim3(16,141,1),256,0,stream>>>(
            hidb, wit + (size_t)l*1048576, ffb, bi, (long)l*2048,
            NTOK_N, 2048, 512, 512, 512, 2048, 2048, 0, flag);
        gemm_k<128,128,EPI_BF16R><<<dim3(4,141,1),256,0,stream>>>(
            ffb, wft + (size_t)l*1048576, tmp16, bfv, (long)l*512,
            NTOK_N, 512, 2048, 2048, 2048, 512, 512, 0, flag);
        ln_residual_k<<<NTOK_N,256,0,stream>>>(tmp16, hidf, hidb, l2g, l2b, (long)l*512,
                                               (l == NL_N-1) ? d_out : (void*)hidb,
                                               (l == NL_N-1) ? 1 : 0, flag);
    }
}